// Round 4
// baseline (345.312 us; speedup 1.0000x reference)
//
#include <hip/hip_runtime.h>
#include <hip/hip_bf16.h>

#define B_ 4
#define L_ 2
#define P_ 100
#define TPP_ 64
#define D_ 768
#define G_ 10
#define T_ (P_ * TPP_)   // 6400
#define NC_ (2 * D_)     // 1536
#define NT_ (D_ / 32)    // 24 K-steps

typedef __attribute__((ext_vector_type(8))) short bf16x8;
typedef __attribute__((ext_vector_type(4))) float f32x4;

__device__ __forceinline__ unsigned short f2bf(float f) {
    __hip_bfloat16 h = __float2bfloat16(f);
    return *reinterpret_cast<unsigned short*>(&h);
}
__device__ __forceinline__ float bfu2f(unsigned short u) {
    return __uint_as_float(((unsigned int)u) << 16);
}

__device__ __forceinline__ void gload_lds16(const void* g, void* l) {
    __builtin_amdgcn_global_load_lds(
        (const __attribute__((address_space(1))) void*)g,
        (__attribute__((address_space(3))) void*)l, 16, 0, 0);
}

// Latin-square slot swizzle (kept; functionally verified in r3)
__device__ __forceinline__ int swz_m(int r) { return (r & 3) ^ ((r >> 2) & 3); }

// ---------------------------------------------------------------------------
// P1: n0<768 blocks: Wpe_nat[b][k][n] = W_p[D+k][n] + a[k]*W_p[2D+k][n]  (natural)
//     n0>=768   :    Wbig[b][n][k]   = W_t[D+k][n-768] + a[k]*W_t[2D+k][n-768] (transposed)
// ---------------------------------------------------------------------------
__global__ __launch_bounds__(256) void prep_wct(
    const float* __restrict__ answer, const float* __restrict__ W_p,
    const float* __restrict__ W_t, __hip_bfloat16* __restrict__ Wpe_nat,
    __hip_bfloat16* __restrict__ Wbig)
{
    __shared__ float lds[64][65];
    __shared__ float a_s[64];
    const int n0 = blockIdx.x * 64;       // 0..1535
    const int k0 = blockIdx.y * 64;       // 0..767
    const int b  = blockIdx.z;
    const int tid = threadIdx.x;

    if (tid < 64) a_s[tid] = answer[((size_t)b * L_ + (L_ - 1)) * D_ + k0 + tid];
    __syncthreads();

    if (n0 < D_) {
        // natural layout, no transpose needed
#pragma unroll
        for (int i = 0; i < 16; ++i) {
            int k = (tid >> 6) + i * 4;
            int n = tid & 63;
            float v = W_p[(size_t)(D_ + k0 + k) * D_ + n0 + n] +
                      a_s[k] * W_p[(size_t)(2 * D_ + k0 + k) * D_ + n0 + n];
            Wpe_nat[(size_t)b * D_ * D_ + (size_t)(k0 + k) * D_ + n0 + n] =
                __float2bfloat16(v);
        }
    } else {
        const int nn0 = n0 - D_;
#pragma unroll
        for (int i = 0; i < 16; ++i) {
            int k = (tid >> 6) + i * 4;
            int n = tid & 63;
            lds[k][n] = W_t[(size_t)(D_ + k0 + k) * D_ + nn0 + n] +
                        a_s[k] * W_t[(size_t)(2 * D_ + k0 + k) * D_ + nn0 + n];
        }
        __syncthreads();
#pragma unroll
        for (int j = 0; j < 16; ++j) {
            int n = (tid >> 6) + j * 4;
            int kk = tid & 63;
            Wbig[((size_t)b * NC_ + n0 + n) * D_ + k0 + kk] =
                __float2bfloat16(lds[kk][n]);
        }
    }
}

// ---------------------------------------------------------------------------
// P2: c_p[b][d], c_t[b][d]
// ---------------------------------------------------------------------------
__global__ __launch_bounds__(512) void prep_const(
    const float* __restrict__ answer,
    const float* __restrict__ W_p, const float* __restrict__ b_p,
    const float* __restrict__ W_t, const float* __restrict__ b_t,
    float* __restrict__ c_p, float* __restrict__ c_t)
{
    const int b = blockIdx.x;
    const int d = blockIdx.y * 64 + (threadIdx.x & 63);
    const int ks = threadIdx.x >> 6;
    const float* a = answer + ((size_t)b * L_ + (L_ - 1)) * D_;
    float sp = 0.f, st = 0.f;
    for (int k = ks; k < D_; k += 8) {
        float av = a[k];
        sp += av * W_p[(size_t)k * D_ + d];
        st += av * W_t[(size_t)k * D_ + d];
    }
    __shared__ float red[2][8][64];
    red[0][ks][threadIdx.x & 63] = sp;
    red[1][ks][threadIdx.x & 63] = st;
    __syncthreads();
    if (ks == 0) {
        float s1 = b_p[d], s2 = b_t[d];
#pragma unroll
        for (int i = 0; i < 8; ++i) {
            s1 += red[0][i][threadIdx.x & 63];
            s2 += red[1][i][threadIdx.x & 63];
        }
        c_p[b * D_ + d] = s1;
        c_t[b * D_ + d] = s2;
    }
}

// ---------------------------------------------------------------------------
// P2b: cc[b][n] = b1[n] + sum_d c_p[b][d]*W1[d][n]   (W1a half: d<768)
// ---------------------------------------------------------------------------
__global__ __launch_bounds__(512) void prep_cc(
    const float* __restrict__ c_p, const float* __restrict__ W1,
    const float* __restrict__ b1, float* __restrict__ cc)
{
    const int b = blockIdx.x;
    const int n = blockIdx.y * 64 + (threadIdx.x & 63);
    const int ks = threadIdx.x >> 6;
    float s = 0.f;
    for (int d = ks; d < D_; d += 8)
        s += c_p[b * D_ + d] * W1[(size_t)d * D_ + n];
    __shared__ float red[8][64];
    red[ks][threadIdx.x & 63] = s;
    __syncthreads();
    if (ks == 0) {
        float tot = b1[n];
#pragma unroll
        for (int i = 0; i < 8; ++i) tot += red[i][threadIdx.x & 63];
        cc[b * D_ + n] = tot;
    }
}

// ---------------------------------------------------------------------------
// P3: q slice (L-1) fp32 -> bf16
// ---------------------------------------------------------------------------
__global__ __launch_bounds__(256) void conv_q(
    const float* __restrict__ q, __hip_bfloat16* __restrict__ qb)
{
    size_t base = ((size_t)blockIdx.x * 256 + threadIdx.x) * 4;
    int b = (int)(base / ((size_t)T_ * D_));
    size_t off = base % ((size_t)T_ * D_);
    float4 v = *reinterpret_cast<const float4*>(
        &q[((size_t)b * L_ + (L_ - 1)) * (size_t)T_ * D_ + off]);
    ushort4 o;
    o.x = f2bf(v.x); o.y = f2bf(v.y); o.z = f2bf(v.z); o.w = f2bf(v.w);
    *reinterpret_cast<ushort4*>(&qb[base]) = o;
}

// ---------------------------------------------------------------------------
// P4: W1 -> W1at[n][k]=W1[k][n] (k<768), W1bt[n][k]=W1[768+k][n]
// ---------------------------------------------------------------------------
__global__ __launch_bounds__(256) void prep_w1t(
    const float* __restrict__ W1, __hip_bfloat16* __restrict__ W1at,
    __hip_bfloat16* __restrict__ W1bt)
{
    __shared__ float lds[64][65];
    const int n0 = blockIdx.x * 64;
    const int k0 = blockIdx.y * 64;
    const int tid = threadIdx.x;
#pragma unroll
    for (int i = 0; i < 16; ++i) {
        int k = (tid >> 6) + i * 4;
        int n = tid & 63;
        lds[k][n] = W1[(size_t)(k0 + k) * D_ + n0 + n];
    }
    __syncthreads();
    __hip_bfloat16* dst = (k0 < D_) ? W1at : W1bt;
    const int kk0 = (k0 < D_) ? k0 : k0 - D_;
#pragma unroll
    for (int j = 0; j < 16; ++j) {
        int n = (tid >> 6) + j * 4;
        int kk = tid & 63;
        dst[(size_t)(n0 + n) * D_ + kk0 + kk] = __float2bfloat16(lds[kk][n]);
    }
}

// ---------------------------------------------------------------------------
// P5: per-batch passage lists per group (counting sort, 1 thread/batch)
// ---------------------------------------------------------------------------
__global__ void build_groups(const int* __restrict__ tids,
                             int* __restrict__ glist, int* __restrict__ goff)
{
    int b = threadIdx.x;
    if (b >= B_) return;
    int cnt[G_];
    for (int g = 0; g < G_; ++g) cnt[g] = 0;
    for (int p = 0; p < P_; ++p) cnt[tids[b * P_ + p]]++;
    int off[G_ + 1];
    off[0] = 0;
    for (int g = 0; g < G_; ++g) off[g + 1] = off[g] + cnt[g];
    for (int g = 0; g <= G_; ++g) goff[b * (G_ + 1) + g] = off[g];
    int cur[G_];
    for (int g = 0; g < G_; ++g) cur[g] = off[g];
    for (int p = 0; p < P_; ++p) {
        int g = tids[b * P_ + p];
        glist[b * P_ + cur[g]++] = p;
    }
}

// ---------------------------------------------------------------------------
// K1: C1t = W1at x Wpe_nat[b]  ->  Wbig[b] lower half (rows 0..767)
//     O[n][k] = sum_d W1at[n][d] * Wpe_nat[b][k][d]
// ---------------------------------------------------------------------------
__global__ __launch_bounds__(256) void gemm_c1(
    const __hip_bfloat16* __restrict__ W1at,
    const __hip_bfloat16* __restrict__ Wpe_nat,
    __hip_bfloat16* __restrict__ Wbig)
{
    const int tm = blockIdx.x, tn = blockIdx.y, b = blockIdx.z;

    __shared__ __align__(16) __hip_bfloat16 As[128][32];
    __shared__ __align__(16) __hip_bfloat16 Bs[128][32];

    const int tid = threadIdx.x;
    const int lane = tid & 63;
    const int w = tid >> 6;
    const int wm = w & 1, wn = w >> 1;

    const __hip_bfloat16* Ab = W1at + (size_t)tm * 128 * D_;
    const __hip_bfloat16* Bb = Wpe_nat + (size_t)b * D_ * D_ + (size_t)tn * 128 * D_;

    f32x4 acc[4][4];
#pragma unroll
    for (int i = 0; i < 4; ++i)
#pragma unroll
        for (int j = 0; j < 4; ++j)
#pragma unroll
            for (int e = 0; e < 4; ++e) acc[i][j][e] = 0.0f;

    const int srow = lane >> 2;
    const int scol = ((lane & 3) ^ swz_m(srow)) * 8;
    const int rr = lane & 15;
    const int rslot = ((lane >> 4) ^ swz_m(rr)) * 8;

    for (int k0 = 0; k0 < D_; k0 += 32) {
#pragma unroll
        for (int i = 0; i < 2; ++i) {
            int c = w * 2 + i;
            gload_lds16(Ab + (size_t)(c * 16 + srow) * D_ + k0 + scol, &As[c * 16][0]);
            gload_lds16(Bb + (size_t)(c * 16 + srow) * D_ + k0 + scol, &Bs[c * 16][0]);
        }
        __syncthreads();
        bf16x8 af[4], bfr[4];
#pragma unroll
        for (int mi = 0; mi < 4; ++mi)
            af[mi] = *reinterpret_cast<const bf16x8*>(&As[wm * 64 + mi * 16 + rr][rslot]);
#pragma unroll
        for (int ni = 0; ni < 4; ++ni)
            bfr[ni] = *reinterpret_cast<const bf16x8*>(&Bs[wn * 64 + ni * 16 + rr][rslot]);
#pragma unroll
        for (int mi = 0; mi < 4; ++mi)
#pragma unroll
            for (int ni = 0; ni < 4; ++ni)
                acc[mi][ni] = __builtin_amdgcn_mfma_f32_16x16x32_bf16(
                    af[mi], bfr[ni], acc[mi][ni], 0, 0, 0);
        __syncthreads();
    }

#pragma unroll
    for (int mi = 0; mi < 4; ++mi)
#pragma unroll
        for (int ni = 0; ni < 4; ++ni) {
            int col = tn * 128 + wn * 64 + ni * 16 + (lane & 15);
            int row = tm * 128 + wm * 64 + mi * 16 + (lane >> 4) * 4;
#pragma unroll
            for (int e = 0; e < 4; ++e)
                Wbig[(size_t)b * NC_ * D_ + (size_t)(row + e) * D_ + col] =
                    __float2bfloat16(acc[mi][ni][e]);
        }
}

// ---------------------------------------------------------------------------
// K2: main GEMM, double-buffered:  [psW | ts] = qb @ Wbig[b]^T + [cc | c_t]
// ---------------------------------------------------------------------------
__global__ __launch_bounds__(256) void gemm_main(
    const __hip_bfloat16* __restrict__ qb,
    const __hip_bfloat16* __restrict__ Wbig,
    const float* __restrict__ cc, const float* __restrict__ c_t,
    __hip_bfloat16* __restrict__ psW, __hip_bfloat16* __restrict__ ts)
{
    const int tm = blockIdx.x, tn = blockIdx.y, b = blockIdx.z;

    __shared__ __align__(16) __hip_bfloat16 As[2][128][32];   // 16 KB
    __shared__ __align__(16) __hip_bfloat16 Bs[2][128][32];   // 16 KB

    const int tid = threadIdx.x;
    const int lane = tid & 63;
    const int w = tid >> 6;
    const int wm = w & 1, wn = w >> 1;

    const __hip_bfloat16* Ab = qb + (size_t)b * T_ * D_ + (size_t)tm * 128 * D_;
    const __hip_bfloat16* Bb = Wbig + (size_t)b * NC_ * D_ + (size_t)tn * 128 * D_;

    const int srow = lane >> 2;
    const int scol = ((lane & 3) ^ swz_m(srow)) * 8;
    // per-thread global sources for this wave's two 16-row chunks
    const __hip_bfloat16* gA0 = Ab + (size_t)(w * 32 + srow) * D_ + scol;
    const __hip_bfloat16* gA1 = Ab + (size_t)(w * 32 + 16 + srow) * D_ + scol;
    const __hip_bfloat16* gB0 = Bb + (size_t)(w * 32 + srow) * D_ + scol;
    const __hip_bfloat16* gB1 = Bb + (size_t)(w * 32 + 16 + srow) * D_ + scol;

    f32x4 acc[4][4];
#pragma unroll
    for (int i = 0; i < 4; ++i)
#pragma unroll
        for (int j = 0; j < 4; ++j)
#pragma unroll
            for (int e = 0; e < 4; ++e) acc[i][j][e] = 0.0f;

    const int rr = lane & 15;
    const int rslot = ((lane >> 4) ^ swz_m(rr)) * 8;

    auto stage = [&](int buf, int t) {
        const size_t ko = (size_t)t * 32;
        gload_lds16(gA0 + ko, &As[buf][w * 32][0]);
        gload_lds16(gA1 + ko, &As[buf][w * 32 + 16][0]);
        gload_lds16(gB0 + ko, &Bs[buf][w * 32][0]);
        gload_lds16(gB1 + ko, &Bs[buf][w * 32 + 16][0]);
    };

    stage(0, 0);
    __syncthreads();

    for (int t = 0; t < NT_; ++t) {
        const int cur = t & 1;
        if (t + 1 < NT_) stage(cur ^ 1, t + 1);   // loads fly during compute
        bf16x8 af[4], bfr[4];
#pragma unroll
        for (int mi = 0; mi < 4; ++mi)
            af[mi] = *reinterpret_cast<const bf16x8*>(
                &As[cur][wm * 64 + mi * 16 + rr][rslot]);
#pragma unroll
        for (int ni = 0; ni < 4; ++ni)
            bfr[ni] = *reinterpret_cast<const bf16x8*>(
                &Bs[cur][wn * 64 + ni * 16 + rr][rslot]);
#pragma unroll
        for (int mi = 0; mi < 4; ++mi)
#pragma unroll
            for (int ni = 0; ni < 4; ++ni)
                acc[mi][ni] = __builtin_amdgcn_mfma_f32_16x16x32_bf16(
                    af[mi], bfr[ni], acc[mi][ni], 0, 0, 0);
        __syncthreads();   // drains vmcnt (stage done) + protects buffer reuse
    }

#pragma unroll
    for (int mi = 0; mi < 4; ++mi)
#pragma unroll
        for (int ni = 0; ni < 4; ++ni) {
            int col = tn * 128 + wn * 64 + ni * 16 + (lane & 15);
            int rb  = tm * 128 + wm * 64 + mi * 16 + (lane >> 4) * 4;
#pragma unroll
            for (int e = 0; e < 4; ++e) {
                int r = rb + e;
                float v = acc[mi][ni][e];
                if (col < D_)
                    psW[((size_t)b * T_ + r) * D_ + col] =
                        __float2bfloat16(v + cc[b * D_ + col]);
                else
                    ts[((size_t)b * T_ + r) * D_ + col - D_] =
                        __float2bfloat16(v + c_t[b * D_ + col - D_]);
            }
        }
}

// ---------------------------------------------------------------------------
// K3: segment max via group lists; 4 d's per thread (ushort4)
// ---------------------------------------------------------------------------
__global__ __launch_bounds__(256) void segmax_kernel(
    const __hip_bfloat16* __restrict__ ts, const int* __restrict__ glist,
    const int* __restrict__ goff, __hip_bfloat16* __restrict__ sm)
{
    int idx = blockIdx.x * 256 + threadIdx.x;   // < B*TPP*(D/4) exact
    int d4 = idx % (D_ / 4);
    int bt = idx / (D_ / 4);
    int t = bt % TPP_;
    int b = bt / TPP_;

    const ushort4* base =
        reinterpret_cast<const ushort4*>(ts + ((size_t)b * T_ + t) * D_) + d4;

    for (int g = 0; g < G_; ++g) {
        float m0 = -1e30f, m1 = -1e30f, m2 = -1e30f, m3 = -1e30f;
        int i0 = goff[b * (G_ + 1) + g], i1 = goff[b * (G_ + 1) + g + 1];
        for (int i = i0; i < i1; ++i) {
            int p = glist[b * P_ + i];
            ushort4 u = base[(size_t)p * TPP_ * (D_ / 4)];
            m0 = fmaxf(m0, bfu2f(u.x));
            m1 = fmaxf(m1, bfu2f(u.y));
            m2 = fmaxf(m2, bfu2f(u.z));
            m3 = fmaxf(m3, bfu2f(u.w));
        }
        ushort4 o;
        o.x = f2bf(m0); o.y = f2bf(m1); o.z = f2bf(m2); o.w = f2bf(m3);
        reinterpret_cast<ushort4*>(
            sm + (((size_t)b * G_ + g) * TPP_ + t) * D_)[d4] = o;
    }
}

// ---------------------------------------------------------------------------
// K4: smW = sm @ W1bt^T   (M=2560, N=768, K=768)
// ---------------------------------------------------------------------------
__global__ __launch_bounds__(256) void gemm_smw(
    const __hip_bfloat16* __restrict__ sm, const __hip_bfloat16* __restrict__ W1bt,
    __hip_bfloat16* __restrict__ smW)
{
    const int tm = blockIdx.x, tn = blockIdx.y;

    __shared__ __align__(16) __hip_bfloat16 As[128][32];
    __shared__ __align__(16) __hip_bfloat16 Bs[128][32];

    const int tid = threadIdx.x;
    const int lane = tid & 63;
    const int w = tid >> 6;
    const int wm = w & 1, wn = w >> 1;

    const __hip_bfloat16* Ab = sm + (size_t)tm * 128 * D_;
    const __hip_bfloat16* Bb = W1bt + (size_t)tn * 128 * D_;

    f32x4 acc[4][4];
#pragma unroll
    for (int i = 0; i < 4; ++i)
#pragma unroll
        for (int j = 0; j < 4; ++j)
#pragma unroll
            for (int e = 0; e < 4; ++e) acc[i][j][e] = 0.0f;

    const int srow = lane >> 2;
    const int scol = ((lane & 3) ^ swz_m(srow)) * 8;
    const int rr = lane & 15;
    const int rslot = ((lane >> 4) ^ swz_m(rr)) * 8;

    for (int k0 = 0; k0 < D_; k0 += 32) {
#pragma unroll
        for (int i = 0; i < 2; ++i) {
            int c = w * 2 + i;
            gload_lds16(Ab + (size_t)(c * 16 + srow) * D_ + k0 + scol, &As[c * 16][0]);
            gload_lds16(Bb + (size_t)(c * 16 + srow) * D_ + k0 + scol, &Bs[c * 16][0]);
        }
        __syncthreads();
        bf16x8 af[4], bfr[4];
#pragma unroll
        for (int mi = 0; mi < 4; ++mi)
            af[mi] = *reinterpret_cast<const bf16x8*>(&As[wm * 64 + mi * 16 + rr][rslot]);
#pragma unroll
        for (int ni = 0; ni < 4; ++ni)
            bfr[ni] = *reinterpret_cast<const bf16x8*>(&Bs[wn * 64 + ni * 16 + rr][rslot]);
#pragma unroll
        for (int mi = 0; mi < 4; ++mi)
#pragma unroll
            for (int ni = 0; ni < 4; ++ni)
                acc[mi][ni] = __builtin_amdgcn_mfma_f32_16x16x32_bf16(
                    af[mi], bfr[ni], acc[mi][ni], 0, 0, 0);
        __syncthreads();
    }

#pragma unroll
    for (int mi = 0; mi < 4; ++mi)
#pragma unroll
        for (int ni = 0; ni < 4; ++ni) {
            int col = tn * 128 + wn * 64 + ni * 16 + (lane & 15);
            int rb  = tm * 128 + wm * 64 + mi * 16 + (lane >> 4) * 4;
#pragma unroll
            for (int e = 0; e < 4; ++e)
                smW[(size_t)(rb + e) * D_ + col] = __float2bfloat16(acc[mi][ni][e]);
        }
}

// ---------------------------------------------------------------------------
// K5: out[b][p] = sum_t mask * ( sum_n relu(psW + smW[g]) * W2 + b2 )
// ---------------------------------------------------------------------------
__global__ __launch_bounds__(256) void score_final(
    const __hip_bfloat16* __restrict__ psW, const __hip_bfloat16* __restrict__ smW,
    const int* __restrict__ tids, const float* __restrict__ W2,
    const float* __restrict__ b2, const float* __restrict__ mask,
    float* __restrict__ out)
{
    const int bp = blockIdx.x;   // 0..399
    const int b = bp / P_, p = bp % P_;
    const int lane = threadIdx.x & 63;
    const int w = threadIdx.x >> 6;
    const int g = tids[bp];

    float w2r[3][4];
#pragma unroll
    for (int j = 0; j < 3; ++j)
#pragma unroll
        for (int e = 0; e < 4; ++e) w2r[j][e] = W2[(lane + 64 * j) * 4 + e];
    const float b2v = b2[0];

    const __hip_bfloat16* pb = psW + ((size_t)b * T_ + (size_t)p * TPP_) * D_;
    const __hip_bfloat16* sb = smW + (((size_t)b * G_ + g) * TPP_) * D_;

    float acc = 0.0f;
    for (int t = w; t < TPP_; t += 4) {
        const ushort4* r1 = reinterpret_cast<const ushort4*>(pb + (size_t)t * D_);
        const ushort4* r2 = reinterpret_cast<const ushort4*>(sb + (size_t)t * D_);
        float s = 0.0f;
#pragma unroll
        for (int j = 0; j < 3; ++j) {
            ushort4 u1 = r1[lane + 64 * j];
            ushort4 u2 = r2[lane + 64 * j];
            s += fmaxf(bfu2f(u1.x) + bfu2f(u2.x), 0.f) * w2r[j][0];
            s += fmaxf(bfu2f(u1.y) + bfu2f(u2.y), 0.f) * w2r[j][1];
            s += fmaxf(bfu2f(u1.z) + bfu2f(u2.z), 0.f) * w2r[j][2];
            s += fmaxf(bfu2f(u1.w) + bfu2f(u2.w), 0.f) * w2r[j][3];
        }
#pragma unroll
        for (int off = 32; off >= 1; off >>= 1) s += __shfl_xor(s, off);
        if (lane == 0) acc += mask[(size_t)bp * TPP_ + t] * (s + b2v);
    }

    __shared__ float partial[4];
    if (lane == 0) partial[w] = acc;
    __syncthreads();
    if (threadIdx.x == 0)
        out[bp] = partial[0] + partial[1] + partial[2] + partial[3];
}

// ---------------------------------------------------------------------------
extern "C" void kernel_launch(void* const* d_in, const int* in_sizes, int n_in,
                              void* d_out, int out_size, void* d_ws, size_t ws_size,
                              hipStream_t stream)
{
    const float* answer = (const float*)d_in[0];
    const float* qps    = (const float*)d_in[1];
    const float* mask   = (const float*)d_in[2];
    const int*   tids   = (const int*)d_in[3];
    // d_in[4] = fusion_scores: unused by the reference
    const float* W_p = (const float*)d_in[5];
    const float* b_p = (const float*)d_in[6];
    const float* W_t = (const float*)d_in[7];
    const float* b_t = (const float*)d_in[8];
    const float* W1  = (const float*)d_in[9];
    const float* b1  = (const float*)d_in[10];
    const float* W2  = (const float*)d_in[11];
    const float* b2  = (const float*)d_in[12];
    float* out = (float*)d_out;

    char* ws = (char*)d_ws;
    __hip_bfloat16* Wpe_nat = (__hip_bfloat16*)ws; ws += (size_t)B_ * D_ * D_ * 2;   // 4.72 MB
    __hip_bfloat16* Wbig    = (__hip_bfloat16*)ws; ws += (size_t)B_ * NC_ * D_ * 2;  // 9.44 MB
    float* c_p = (float*)ws;                   ws += (size_t)B_ * D_ * 4;
    float* c_t = (float*)ws;                   ws += (size_t)B_ * D_ * 4;
    float* cc  = (float*)ws;                   ws += (size_t)B_ * D_ * 4;
    __hip_bfloat16* qb = (__hip_bfloat16*)ws;  ws += (size_t)B_ * T_ * D_ * 2;       // 39.3 MB
    __hip_bfloat16* psW = (__hip_bfloat16*)ws; ws += (size_t)B_ * T_ * D_ * 2;       // 39.3 MB
    __hip_bfloat16* ts = (__hip_bfloat16*)ws;  ws += (size_t)B_ * T_ * D_ * 2;       // 39.3 MB
    __hip_bfloat16* sm = (__hip_bfloat16*)ws;  ws += (size_t)B_ * G_ * TPP_ * D_ * 2;   // 3.93 MB
    __hip_bfloat16* smW = (__hip_bfloat16*)ws; ws += (size_t)B_ * G_ * TPP_ * D_ * 2;   // 3.93 MB
    __hip_bfloat16* W1at = (__hip_bfloat16*)ws; ws += (size_t)D_ * D_ * 2;           // 1.18 MB
    __hip_bfloat16* W1bt = (__hip_bfloat16*)ws; ws += (size_t)D_ * D_ * 2;           // 1.18 MB
    int* glist = (int*)ws;                     ws += B_ * P_ * 4;
    int* goff  = (int*)ws;                     ws += B_ * (G_ + 1) * 4;

    prep_wct<<<dim3(NC_ / 64, D_ / 64, B_), 256, 0, stream>>>(
        answer, W_p, W_t, Wpe_nat, Wbig);
    prep_const<<<dim3(B_, D_ / 64), 512, 0, stream>>>(
        answer, W_p, b_p, W_t, b_t, c_p, c_t);
    prep_cc<<<dim3(B_, D_ / 64), 512, 0, stream>>>(c_p, W1, b1, cc);
    conv_q<<<(B_ * T_ * D_) / (256 * 4), 256, 0, stream>>>(qps, qb);
    prep_w1t<<<dim3(D_ / 64, NC_ / 64), 256, 0, stream>>>(W1, W1at, W1bt);
    build_groups<<<1, 64, 0, stream>>>(tids, glist, goff);
    gemm_c1<<<dim3(D_ / 128, D_ / 128, B_), 256, 0, stream>>>(W1at, Wpe_nat, Wbig);
    gemm_main<<<dim3(T_ / 128, NC_ / 128, B_), 256, 0, stream>>>(
        qb, Wbig, cc, c_t, psW, ts);
    segmax_kernel<<<(B_ * TPP_ * (D_ / 4)) / 256, 256, 0, stream>>>(
        ts, glist, goff, sm);
    gemm_smw<<<dim3((B_ * G_ * TPP_) / 128, D_ / 128), 256, 0, stream>>>(
        sm, W1bt, smW);
    score_final<<<B_ * P_, 256, 0, stream>>>(psW, smW, tids, W2, b2, mask, out);
}

// Round 5
// 343.829 us; speedup vs baseline: 1.0043x; 1.0043x over previous
//
#include <hip/hip_runtime.h>
#include <hip/hip_bf16.h>

#define B_ 4
#define L_ 2
#define P_ 100
#define TPP_ 64
#define D_ 768
#define G_ 10
#define T_ (P_ * TPP_)   // 6400
#define NC_ (2 * D_)     // 1536

typedef __attribute__((ext_vector_type(8))) short bf16x8;
typedef __attribute__((ext_vector_type(4))) float f32x4;

__device__ __forceinline__ unsigned short f2bf(float f) {
    __hip_bfloat16 h = __float2bfloat16(f);
    return *reinterpret_cast<unsigned short*>(&h);
}
__device__ __forceinline__ float bfu2f(unsigned short u) {
    return __uint_as_float(((unsigned int)u) << 16);
}

__device__ __forceinline__ void gload_lds16(const void* g, void* l) {
    __builtin_amdgcn_global_load_lds(
        (const __attribute__((address_space(1))) void*)g,
        (__attribute__((address_space(3))) void*)l, 16, 0, 0);
}

// bf16 B-side Latin-square slot swizzle (16-row period), verified r3/r4
__device__ __forceinline__ int swz_m(int r) { return (r & 3) ^ ((r >> 2) & 3); }

// ---------------------------------------------------------------------------
// P1: n0<768: Wpe_nat[b][k][d] (natural) ; n0>=768: Wbig[b][n][k] (transposed)
// ---------------------------------------------------------------------------
__global__ __launch_bounds__(256) void prep_wct(
    const float* __restrict__ answer, const float* __restrict__ W_p,
    const float* __restrict__ W_t, __hip_bfloat16* __restrict__ Wpe_nat,
    __hip_bfloat16* __restrict__ Wbig)
{
    __shared__ float lds[64][65];
    __shared__ float a_s[64];
    const int n0 = blockIdx.x * 64;       // 0..1535
    const int k0 = blockIdx.y * 64;       // 0..767
    const int b  = blockIdx.z;
    const int tid = threadIdx.x;

    if (tid < 64) a_s[tid] = answer[((size_t)b * L_ + (L_ - 1)) * D_ + k0 + tid];
    __syncthreads();

    if (n0 < D_) {
#pragma unroll
        for (int i = 0; i < 16; ++i) {
            int k = (tid >> 6) + i * 4;
            int n = tid & 63;
            float v = W_p[(size_t)(D_ + k0 + k) * D_ + n0 + n] +
                      a_s[k] * W_p[(size_t)(2 * D_ + k0 + k) * D_ + n0 + n];
            Wpe_nat[(size_t)b * D_ * D_ + (size_t)(k0 + k) * D_ + n0 + n] =
                __float2bfloat16(v);
        }
    } else {
        const int nn0 = n0 - D_;
#pragma unroll
        for (int i = 0; i < 16; ++i) {
            int k = (tid >> 6) + i * 4;
            int n = tid & 63;
            lds[k][n] = W_t[(size_t)(D_ + k0 + k) * D_ + nn0 + n] +
                        a_s[k] * W_t[(size_t)(2 * D_ + k0 + k) * D_ + nn0 + n];
        }
        __syncthreads();
#pragma unroll
        for (int j = 0; j < 16; ++j) {
            int n = (tid >> 6) + j * 4;
            int kk = tid & 63;
            Wbig[((size_t)b * NC_ + n0 + n) * D_ + k0 + kk] =
                __float2bfloat16(lds[kk][n]);
        }
    }
}

// ---------------------------------------------------------------------------
// P2: c_p[b][d], c_t[b][d]
// ---------------------------------------------------------------------------
__global__ __launch_bounds__(512) void prep_const(
    const float* __restrict__ answer,
    const float* __restrict__ W_p, const float* __restrict__ b_p,
    const float* __restrict__ W_t, const float* __restrict__ b_t,
    float* __restrict__ c_p, float* __restrict__ c_t)
{
    const int b = blockIdx.x;
    const int d = blockIdx.y * 64 + (threadIdx.x & 63);
    const int ks = threadIdx.x >> 6;
    const float* a = answer + ((size_t)b * L_ + (L_ - 1)) * D_;
    float sp = 0.f, st = 0.f;
#pragma unroll 4
    for (int k = ks; k < D_; k += 8) {
        float av = a[k];
        sp += av * W_p[(size_t)k * D_ + d];
        st += av * W_t[(size_t)k * D_ + d];
    }
    __shared__ float red[2][8][64];
    red[0][ks][threadIdx.x & 63] = sp;
    red[1][ks][threadIdx.x & 63] = st;
    __syncthreads();
    if (ks == 0) {
        float s1 = b_p[d], s2 = b_t[d];
#pragma unroll
        for (int i = 0; i < 8; ++i) {
            s1 += red[0][i][threadIdx.x & 63];
            s2 += red[1][i][threadIdx.x & 63];
        }
        c_p[b * D_ + d] = s1;
        c_t[b * D_ + d] = s2;
    }
}

// ---------------------------------------------------------------------------
// P2b: cc[b][n] = b1[n] + sum_d c_p[b][d]*W1[d][n]
// ---------------------------------------------------------------------------
__global__ __launch_bounds__(512) void prep_cc(
    const float* __restrict__ c_p, const float* __restrict__ W1,
    const float* __restrict__ b1, float* __restrict__ cc)
{
    const int b = blockIdx.x;
    const int n = blockIdx.y * 64 + (threadIdx.x & 63);
    const int ks = threadIdx.x >> 6;
    float s = 0.f;
#pragma unroll 4
    for (int d = ks; d < D_; d += 8)
        s += c_p[b * D_ + d] * W1[(size_t)d * D_ + n];
    __shared__ float red[8][64];
    red[ks][threadIdx.x & 63] = s;
    __syncthreads();
    if (ks == 0) {
        float tot = b1[n];
#pragma unroll
        for (int i = 0; i < 8; ++i) tot += red[i][threadIdx.x & 63];
        cc[b * D_ + n] = tot;
    }
}

// ---------------------------------------------------------------------------
// P4: W1 -> W1at[n][k]=W1[k][n] (k<768), W1bt[n][k]=W1[768+k][n]
// ---------------------------------------------------------------------------
__global__ __launch_bounds__(256) void prep_w1t(
    const float* __restrict__ W1, __hip_bfloat16* __restrict__ W1at,
    __hip_bfloat16* __restrict__ W1bt)
{
    __shared__ float lds[64][65];
    const int n0 = blockIdx.x * 64;
    const int k0 = blockIdx.y * 64;
    const int tid = threadIdx.x;
#pragma unroll
    for (int i = 0; i < 16; ++i) {
        int k = (tid >> 6) + i * 4;
        int n = tid & 63;
        lds[k][n] = W1[(size_t)(k0 + k) * D_ + n0 + n];
    }
    __syncthreads();
    __hip_bfloat16* dst = (k0 < D_) ? W1at : W1bt;
    const int kk0 = (k0 < D_) ? k0 : k0 - D_;
#pragma unroll
    for (int j = 0; j < 16; ++j) {
        int n = (tid >> 6) + j * 4;
        int kk = tid & 63;
        dst[(size_t)(n0 + n) * D_ + kk0 + kk] = __float2bfloat16(lds[kk][n]);
    }
}

// ---------------------------------------------------------------------------
// P5: parallel group lists (LDS-atomic counting sort; order-unstable is OK
//     because the segment op is max). One block, 256 threads.
// ---------------------------------------------------------------------------
__global__ __launch_bounds__(256) void build_groups(
    const int* __restrict__ tids, int* __restrict__ glist, int* __restrict__ goff)
{
    __shared__ int cnt[B_][G_];
    __shared__ int off[B_][G_ + 1];
    __shared__ int cur[B_][G_];
    const int tid = threadIdx.x;

    if (tid < B_ * G_) cnt[tid / G_][tid % G_] = 0;
    __syncthreads();
    for (int i = tid; i < B_ * P_; i += 256)
        atomicAdd(&cnt[i / P_][tids[i]], 1);
    __syncthreads();
    if (tid < B_) {
        int o = 0;
        for (int g = 0; g < G_; ++g) { off[tid][g] = o; o += cnt[tid][g]; }
        off[tid][G_] = o;
        for (int g = 0; g <= G_; ++g) goff[tid * (G_ + 1) + g] = off[tid][g];
    }
    __syncthreads();
    if (tid < B_ * G_) cur[tid / G_][tid % G_] = off[tid / G_][tid % G_];
    __syncthreads();
    for (int i = tid; i < B_ * P_; i += 256) {
        int b = i / P_, p = i % P_;
        int slot = atomicAdd(&cur[b][tids[i]], 1);
        glist[b * P_ + slot] = p;
    }
}

// ---------------------------------------------------------------------------
// K1: Wbig[b] lower half:  Wbig[b][j][k] = sum_d W1at[j][d] * Wpe_nat[b][k][d]
// ---------------------------------------------------------------------------
__global__ __launch_bounds__(256) void gemm_c1(
    const __hip_bfloat16* __restrict__ W1at,
    const __hip_bfloat16* __restrict__ Wpe_nat,
    __hip_bfloat16* __restrict__ Wbig)
{
    const int tm = blockIdx.x, tn = blockIdx.y, b = blockIdx.z;

    __shared__ __align__(16) __hip_bfloat16 As[128][32];
    __shared__ __align__(16) __hip_bfloat16 Bs[128][32];

    const int tid = threadIdx.x;
    const int lane = tid & 63;
    const int w = tid >> 6;
    const int wm = w & 1, wn = w >> 1;

    const __hip_bfloat16* Ab = W1at + (size_t)tm * 128 * D_;
    const __hip_bfloat16* Bb = Wpe_nat + (size_t)b * D_ * D_ + (size_t)tn * 128 * D_;

    f32x4 acc[4][4];
#pragma unroll
    for (int i = 0; i < 4; ++i)
#pragma unroll
        for (int j = 0; j < 4; ++j)
#pragma unroll
            for (int e = 0; e < 4; ++e) acc[i][j][e] = 0.0f;

    const int srow = lane >> 2;
    const int scol = ((lane & 3) ^ swz_m(srow)) * 8;
    const int rr = lane & 15;
    const int rslot = ((lane >> 4) ^ swz_m(rr)) * 8;

    for (int k0 = 0; k0 < D_; k0 += 32) {
#pragma unroll
        for (int i = 0; i < 2; ++i) {
            int c = w * 2 + i;
            gload_lds16(Ab + (size_t)(c * 16 + srow) * D_ + k0 + scol, &As[c * 16][0]);
            gload_lds16(Bb + (size_t)(c * 16 + srow) * D_ + k0 + scol, &Bs[c * 16][0]);
        }
        __syncthreads();
        bf16x8 af[4], bfr[4];
#pragma unroll
        for (int mi = 0; mi < 4; ++mi)
            af[mi] = *reinterpret_cast<const bf16x8*>(&As[wm * 64 + mi * 16 + rr][rslot]);
#pragma unroll
        for (int ni = 0; ni < 4; ++ni)
            bfr[ni] = *reinterpret_cast<const bf16x8*>(&Bs[wn * 64 + ni * 16 + rr][rslot]);
#pragma unroll
        for (int mi = 0; mi < 4; ++mi)
#pragma unroll
            for (int ni = 0; ni < 4; ++ni)
                acc[mi][ni] = __builtin_amdgcn_mfma_f32_16x16x32_bf16(
                    af[mi], bfr[ni], acc[mi][ni], 0, 0, 0);
        __syncthreads();
    }

#pragma unroll
    for (int mi = 0; mi < 4; ++mi)
#pragma unroll
        for (int ni = 0; ni < 4; ++ni) {
            int col = tn * 128 + wn * 64 + ni * 16 + (lane & 15);
            int row = tm * 128 + wm * 64 + mi * 16 + (lane >> 4) * 4;
#pragma unroll
            for (int e = 0; e < 4; ++e)
                Wbig[(size_t)b * NC_ * D_ + (size_t)(row + e) * D_ + col] =
                    __float2bfloat16(acc[mi][ni][e]);
        }
}

// ---------------------------------------------------------------------------
// K2: main GEMM, r3 structure, fp32-A staged directly from qps (conv fused).
//     [psW | ts] = q_f32 @ Wbig[b]^T + [cc | c_t]
//     A-swizzle: 32B slots, slot' = slot ^ (row&3), both-sides (rule #21).
// ---------------------------------------------------------------------------
__global__ __launch_bounds__(256) void gemm_main(
    const float* __restrict__ qps,
    const __hip_bfloat16* __restrict__ Wbig,
    const float* __restrict__ cc, const float* __restrict__ c_t,
    __hip_bfloat16* __restrict__ psW, __hip_bfloat16* __restrict__ ts)
{
    const int tm = blockIdx.x, tn = blockIdx.y, b = blockIdx.z;

    __shared__ __align__(16) float Asf[128][32];              // 16 KB (fp32 A)
    __shared__ __align__(16) __hip_bfloat16 Bs[128][32];      // 8 KB

    const int tid = threadIdx.x;
    const int lane = tid & 63;
    const int w = tid >> 6;
    const int wm = w & 1, wn = w >> 1;

    const float* Ab = qps + ((size_t)b * L_ + (L_ - 1)) * (size_t)T_ * D_ +
                      (size_t)tm * 128 * D_;
    const __hip_bfloat16* Bb = Wbig + (size_t)b * NC_ * D_ + (size_t)tn * 128 * D_;

    f32x4 acc[4][4];
#pragma unroll
    for (int i = 0; i < 4; ++i)
#pragma unroll
        for (int j = 0; j < 4; ++j)
#pragma unroll
            for (int e = 0; e < 4; ++e) acc[i][j][e] = 0.0f;

    // A staging: 4 issues/thread; each wave-issue covers 8 rows (fp32, 128B/row)
    const int arow_l = lane >> 3;            // row within 8-row group
    const int aslot  = (lane & 7) >> 1;      // 32B slot 0..3
    const int ahalf  = lane & 1;             // 16B half
    // B staging: 2 issues/thread; each wave-issue covers 16 rows (bf16, 64B/row)
    const int brow_l = lane >> 2;
    const int bslot  = lane & 3;

    const int rr = lane & 15;
    const int h  = lane >> 4;                 // fragment k-slot
    const int rslotB = (h ^ swz_m(rr)) * 8;   // B read swizzle (bf16)
    const int aslotR = (h ^ (rr & 3)) * 8;    // A read swizzle (fp32, floats)

    for (int k0 = 0; k0 < D_; k0 += 32) {
        // ---- stage A (fp32, pre-swizzled source) ----
#pragma unroll
        for (int j = 0; j < 4; ++j) {
            int row = w * 32 + j * 8 + arow_l;
            int ks = ((aslot ^ (row & 3)) << 3) + (ahalf << 2);
            gload_lds16(Ab + (size_t)row * D_ + k0 + ks, &Asf[w * 32 + j * 8][0]);
        }
        // ---- stage B (bf16, pre-swizzled source) ----
#pragma unroll
        for (int i = 0; i < 2; ++i) {
            int row = w * 32 + i * 16 + brow_l;
            int kb = (bslot ^ swz_m(row & 15)) << 3;
            gload_lds16(Bb + (size_t)row * D_ + k0 + kb, &Bs[w * 32 + i * 16][0]);
        }
        __syncthreads();

        bf16x8 af[4], bfr[4];
#pragma unroll
        for (int mi = 0; mi < 4; ++mi) {
            const float* ap = &Asf[wm * 64 + mi * 16 + rr][aslotR];
            float4 lo = *reinterpret_cast<const float4*>(ap);
            float4 hi = *reinterpret_cast<const float4*>(ap + 4);
            bf16x8 r;
            r[0] = (short)f2bf(lo.x); r[1] = (short)f2bf(lo.y);
            r[2] = (short)f2bf(lo.z); r[3] = (short)f2bf(lo.w);
            r[4] = (short)f2bf(hi.x); r[5] = (short)f2bf(hi.y);
            r[6] = (short)f2bf(hi.z); r[7] = (short)f2bf(hi.w);
            af[mi] = r;
        }
#pragma unroll
        for (int ni = 0; ni < 4; ++ni)
            bfr[ni] = *reinterpret_cast<const bf16x8*>(
                &Bs[wn * 64 + ni * 16 + rr][rslotB]);
#pragma unroll
        for (int mi = 0; mi < 4; ++mi)
#pragma unroll
            for (int ni = 0; ni < 4; ++ni)
                acc[mi][ni] = __builtin_amdgcn_mfma_f32_16x16x32_bf16(
                    af[mi], bfr[ni], acc[mi][ni], 0, 0, 0);
        __syncthreads();
    }

#pragma unroll
    for (int ni = 0; ni < 4; ++ni) {
        int col = tn * 128 + wn * 64 + ni * 16 + (lane & 15);
        const bool isP = (col < D_);
        const float cv = isP ? cc[b * D_ + col] : c_t[b * D_ + col - D_];
        __hip_bfloat16* dst = isP ? (psW + (size_t)b * T_ * D_ + col)
                                  : (ts + (size_t)b * T_ * D_ + col - D_);
#pragma unroll
        for (int mi = 0; mi < 4; ++mi) {
            int rb = tm * 128 + wm * 64 + mi * 16 + (lane >> 4) * 4;
#pragma unroll
            for (int e = 0; e < 4; ++e)
                dst[(size_t)(rb + e) * D_] = __float2bfloat16(acc[mi][ni][e] + cv);
        }
    }
}

// ---------------------------------------------------------------------------
// K3: segment max via group lists; 4 d's per thread (ushort4)
// ---------------------------------------------------------------------------
__global__ __launch_bounds__(256) void segmax_kernel(
    const __hip_bfloat16* __restrict__ ts, const int* __restrict__ glist,
    const int* __restrict__ goff, __hip_bfloat16* __restrict__ sm)
{
    int idx = blockIdx.x * 256 + threadIdx.x;   // < B*TPP*(D/4) exact
    int d4 = idx % (D_ / 4);
    int bt = idx / (D_ / 4);
    int t = bt % TPP_;
    int b = bt / TPP_;

    const ushort4* base =
        reinterpret_cast<const ushort4*>(ts + ((size_t)b * T_ + t) * D_) + d4;

    for (int g = 0; g < G_; ++g) {
        float m0 = -1e30f, m1 = -1e30f, m2 = -1e30f, m3 = -1e30f;
        int i0 = goff[b * (G_ + 1) + g], i1 = goff[b * (G_ + 1) + g + 1];
        for (int i = i0; i < i1; ++i) {
            int p = glist[b * P_ + i];
            ushort4 u = base[(size_t)p * TPP_ * (D_ / 4)];
            m0 = fmaxf(m0, bfu2f(u.x));
            m1 = fmaxf(m1, bfu2f(u.y));
            m2 = fmaxf(m2, bfu2f(u.z));
            m3 = fmaxf(m3, bfu2f(u.w));
        }
        ushort4 o;
        o.x = f2bf(m0); o.y = f2bf(m1); o.z = f2bf(m2); o.w = f2bf(m3);
        reinterpret_cast<ushort4*>(
            sm + (((size_t)b * G_ + g) * TPP_ + t) * D_)[d4] = o;
    }
}

// ---------------------------------------------------------------------------
// K4: smW = sm @ W1bt^T   (M=2560, N=768, K=768)
// ---------------------------------------------------------------------------
__global__ __launch_bounds__(256) void gemm_smw(
    const __hip_bfloat16* __restrict__ sm, const __hip_bfloat16* __restrict__ W1bt,
    __hip_bfloat16* __restrict__ smW)
{
    const int tm = blockIdx.x, tn = blockIdx.y;

    __shared__ __align__(16) __hip_bfloat16 As[128][32];
    __shared__ __align__(16) __hip_bfloat16 Bs[128][32];

    const int tid = threadIdx.x;
    const int lane = tid & 63;
    const int w = tid >> 6;
    const int wm = w & 1, wn = w >> 1;

    const __hip_bfloat16* Ab = sm + (size_t)tm * 128 * D_;
    const __hip_bfloat16* Bb = W1bt + (size_t)tn * 128 * D_;

    f32x4 acc[4][4];
#pragma unroll
    for (int i = 0; i < 4; ++i)
#pragma unroll
        for (int j = 0; j < 4; ++j)
#pragma unroll
            for (int e = 0; e < 4; ++e) acc[i][j][e] = 0.0f;

    const int srow = lane >> 2;
    const int scol = ((lane & 3) ^ swz_m(srow)) * 8;
    const int rr = lane & 15;
    const int rslot = ((lane >> 4) ^ swz_m(rr)) * 8;

    for (int k0 = 0; k0 < D_; k0 += 32) {
#pragma unroll
        for (int i = 0; i < 2; ++i) {
            int c = w * 2 + i;
            gload_lds16(Ab + (size_t)(c * 16 + srow) * D_ + k0 + scol, &As[c * 16][0]);
            gload_lds16(Bb + (size_t)(c * 16 + srow) * D_ + k0 + scol, &Bs[c * 16][0]);
        }
        __syncthreads();
        bf16x8 af[4], bfr[4];
#pragma unroll
        for (int mi = 0; mi < 4; ++mi)
            af[mi] = *reinterpret_cast<const bf16x8*>(&As[wm * 64 + mi * 16 + rr][rslot]);
#pragma unroll
        for (int ni = 0; ni < 4; ++ni)
            bfr[ni] = *reinterpret_cast<const bf16x8*>(&Bs[wn * 64 + ni * 16 + rr][rslot]);
#pragma unroll
        for (int mi = 0; mi < 4; ++mi)
#pragma unroll
            for (int ni = 0; ni < 4; ++ni)
                acc[mi][ni] = __builtin_amdgcn_mfma_f32_16x16x32_bf16(
                    af[mi], bfr[ni], acc[mi][ni], 0, 0, 0);
        __syncthreads();
    }

#pragma unroll
    for (int mi = 0; mi < 4; ++mi)
#pragma unroll
        for (int ni = 0; ni < 4; ++ni) {
            int col = tn * 128 + wn * 64 + ni * 16 + (lane & 15);
            int rb  = tm * 128 + wm * 64 + mi * 16 + (lane >> 4) * 4;
#pragma unroll
            for (int e = 0; e < 4; ++e)
                smW[(size_t)(rb + e) * D_ + col] = __float2bfloat16(acc[mi][ni][e]);
        }
}

// ---------------------------------------------------------------------------
// K5: out[b][p] = sum_t mask * ( sum_n relu(psW + smW[g]) * W2 + b2 )
// ---------------------------------------------------------------------------
__global__ __launch_bounds__(256) void score_final(
    const __hip_bfloat16* __restrict__ psW, const __hip_bfloat16* __restrict__ smW,
    const int* __restrict__ tids, const float* __restrict__ W2,
    const float* __restrict__ b2, const float* __restrict__ mask,
    float* __restrict__ out)
{
    const int bp = blockIdx.x;   // 0..399
    const int b = bp / P_, p = bp % P_;
    const int lane = threadIdx.x & 63;
    const int w = threadIdx.x >> 6;
    const int g = tids[bp];

    float w2r[3][4];
#pragma unroll
    for (int j = 0; j < 3; ++j)
#pragma unroll
        for (int e = 0; e < 4; ++e) w2r[j][e] = W2[(lane + 64 * j) * 4 + e];
    const float b2v = b2[0];

    const __hip_bfloat16* pb = psW + ((size_t)b * T_ + (size_t)p * TPP_) * D_;
    const __hip_bfloat16* sb = smW + (((size_t)b * G_ + g) * TPP_) * D_;

    float acc = 0.0f;
    for (int t = w; t < TPP_; t += 4) {
        const ushort4* r1 = reinterpret_cast<const ushort4*>(pb + (size_t)t * D_);
        const ushort4* r2 = reinterpret_cast<const ushort4*>(sb + (size_t)t * D_);
        float s = 0.0f;
#pragma unroll
        for (int j = 0; j < 3; ++j) {
            ushort4 u1 = r1[lane + 64 * j];
            ushort4 u2 = r2[lane + 64 * j];
            s += fmaxf(bfu2f(u1.x) + bfu2f(u2.x), 0.f) * w2r[j][0];
            s += fmaxf(bfu2f(u1.y) + bfu2f(u2.y), 0.f) * w2r[j][1];
            s += fmaxf(bfu2f(u1.z) + bfu2f(u2.z), 0.f) * w2r[j][2];
            s += fmaxf(bfu2f(u1.w) + bfu2f(u2.w), 0.f) * w2r[j][3];
        }
#pragma unroll
        for (int off = 32; off >= 1; off >>= 1) s += __shfl_xor(s, off);
        if (lane == 0) acc += mask[(size_t)bp * TPP_ + t] * (s + b2v);
    }

    __shared__ float partial[4];
    if (lane == 0) partial[w] = acc;
    __syncthreads();
    if (threadIdx.x == 0)
        out[bp] = partial[0] + partial[1] + partial[2] + partial[3];
}

// ---------------------------------------------------------------------------
extern "C" void kernel_launch(void* const* d_in, const int* in_sizes, int n_in,
                              void* d_out, int out_size, void* d_ws, size_t ws_size,
                              hipStream_t stream)
{
    const float* answer = (const float*)d_in[0];
    const float* qps    = (const float*)d_in[1];
    const float* mask   = (const float*)d_in[2];
    const int*   tids   = (const int*)d_in[3];
    // d_in[4] = fusion_scores: unused by the reference
    const float* W_p = (const float*)d_in[5];
    const float* b_p = (const float*)d_in[6];
    const float* W_t = (const float*)d_in[7];
    const float* b_t = (const float*)d_in[8];
    const float* W1  = (const float*)d_in[9];
    const float* b1  = (const float*)d_in[10];
    const float* W2  = (const float*)d_in[11];
    const float* b2  = (const float*)d_in[12];
    float* out = (float*)d_out;

    char* ws = (char*)d_ws;
    __hip_bfloat16* Wpe_nat = (__hip_bfloat16*)ws; ws += (size_t)B_ * D_ * D_ * 2;
    __hip_bfloat16* Wbig    = (__hip_bfloat16*)ws; ws += (size_t)B_ * NC_ * D_ * 2;
    float* c_p = (float*)ws;                   ws += (size_t)B_ * D_ * 4;
    float* c_t = (float*)ws;                   ws += (size_t)B_ * D_ * 4;
    float* cc  = (float*)ws;                   ws += (size_t)B_ * D_ * 4;
    __hip_bfloat16* psW = (__hip_bfloat16*)ws; ws += (size_t)B_ * T_ * D_ * 2;
    __hip_bfloat16* ts = (__hip_bfloat16*)ws;  ws += (size_t)B_ * T_ * D_ * 2;
    __hip_bfloat16* sm = (__hip_bfloat16*)ws;  ws += (size_t)B_ * G_ * TPP_ * D_ * 2;
    __hip_bfloat16* smW = (__hip_bfloat16*)ws; ws += (size_t)B_ * G_ * TPP_ * D_ * 2;
    __hip_bfloat16* W1at = (__hip_bfloat16*)ws; ws += (size_t)D_ * D_ * 2;
    __hip_bfloat16* W1bt = (__hip_bfloat16*)ws; ws += (size_t)D_ * D_ * 2;
    int* glist = (int*)ws;                     ws += B_ * P_ * 4;
    int* goff  = (int*)ws;                     ws += B_ * (G_ + 1) * 4;

    prep_wct<<<dim3(NC_ / 64, D_ / 64, B_), 256, 0, stream>>>(
        answer, W_p, W_t, Wpe_nat, Wbig);
    prep_const<<<dim3(B_, D_ / 64), 512, 0, stream>>>(
        answer, W_p, b_p, W_t, b_t, c_p, c_t);
    prep_cc<<<dim3(B_, D_ / 64), 512, 0, stream>>>(c_p, W1, b1, cc);
    prep_w1t<<<dim3(D_ / 64, NC_ / 64), 256, 0, stream>>>(W1, W1at, W1bt);
    build_groups<<<1, 256, 0, stream>>>(tids, glist, goff);
    gemm_c1<<<dim3(D_ / 128, D_ / 128, B_), 256, 0, stream>>>(W1at, Wpe_nat, Wbig);
    gemm_main<<<dim3(T_ / 128, NC_ / 128, B_), 256, 0, stream>>>(
        qps, Wbig, cc, c_t, psW, ts);
    segmax_kernel<<<(B_ * TPP_ * (D_ / 4)) / 256, 256, 0, stream>>>(
        ts, glist, goff, sm);
    gemm_smw<<<dim3((B_ * G_ * TPP_) / 128, D_ / 128), 256, 0, stream>>>(
        sm, W1bt, smW);
    score_final<<<B_ * P_, 256, 0, stream>>>(psW, smW, tids, W2, b2, mask, out);
}

// Round 6
// 258.265 us; speedup vs baseline: 1.3370x; 1.3313x over previous
//
#include <hip/hip_runtime.h>
#include <hip/hip_bf16.h>

#define B_ 4
#define L_ 2
#define P_ 100
#define TPP_ 64
#define D_ 768
#define G_ 10
#define T_ (P_ * TPP_)   // 6400
#define NC_ (2 * D_)     // 1536

typedef __attribute__((ext_vector_type(8))) short bf16x8;
typedef __attribute__((ext_vector_type(4))) float f32x4;

__device__ __forceinline__ unsigned short f2bf(float f) {
    __hip_bfloat16 h = __float2bfloat16(f);
    return *reinterpret_cast<unsigned short*>(&h);
}
__device__ __forceinline__ float bfu2f(unsigned short u) {
    return __uint_as_float(((unsigned int)u) << 16);
}

__device__ __forceinline__ void gload_lds16(const void* g, void* l) {
    __builtin_amdgcn_global_load_lds(
        (const __attribute__((address_space(1))) void*)g,
        (__attribute__((address_space(3))) void*)l, 16, 0, 0);
}

// ---------------------------------------------------------------------------
// Shared BK=64 MFMA main loop.  LDS rows are 128B (64 bf16); both-sides
// swizzle over 8x16B slots:  LDS[r][s] = G[r][s ^ (r&7)]  (rule #21: linear
// gload_lds dest + pre-swizzled per-lane global source + swizzled read).
// Service-group check: lanes 0..7 of a ds_read_b128 map to 8 distinct slots
// -> conflict-free reads.  12 K-steps (vs 24 at BK=32) halves barrier drains.
// ---------------------------------------------------------------------------
__device__ __forceinline__ void mfma_loop64(
    const __hip_bfloat16* __restrict__ Ag, const __hip_bfloat16* __restrict__ Bg,
    __hip_bfloat16 (*As)[64], __hip_bfloat16 (*Bs)[64],
    int lane, int w, int wm, int wn, f32x4 acc[4][4])
{
    const int rr = lane & 15, h = lane >> 4;
    const int row_l = lane >> 3, slot = lane & 7;
    const int soff = (slot ^ row_l) << 3;   // bf16 offset of this lane's 16B
    for (int k0 = 0; k0 < D_; k0 += 64) {
#pragma unroll
        for (int j = 0; j < 4; ++j) {
            int r = w * 32 + j * 8 + row_l;   // r&7 == row_l
            gload_lds16(Ag + (size_t)r * D_ + k0 + soff, &As[w * 32 + j * 8][0]);
            gload_lds16(Bg + (size_t)r * D_ + k0 + soff, &Bs[w * 32 + j * 8][0]);
        }
        __syncthreads();
#pragma unroll
        for (int ks = 0; ks < 2; ++ks) {
            const int rsl = (((ks << 2) + h) ^ (rr & 7)) << 3;
            bf16x8 af[4], bfr[4];
#pragma unroll
            for (int mi = 0; mi < 4; ++mi)
                af[mi] = *reinterpret_cast<const bf16x8*>(
                    &As[wm * 64 + mi * 16 + rr][rsl]);
#pragma unroll
            for (int ni = 0; ni < 4; ++ni)
                bfr[ni] = *reinterpret_cast<const bf16x8*>(
                    &Bs[wn * 64 + ni * 16 + rr][rsl]);
#pragma unroll
            for (int mi = 0; mi < 4; ++mi)
#pragma unroll
                for (int ni = 0; ni < 4; ++ni)
                    acc[mi][ni] = __builtin_amdgcn_mfma_f32_16x16x32_bf16(
                        af[mi], bfr[ni], acc[mi][ni], 0, 0, 0);
        }
        __syncthreads();
    }
}

// ---------------------------------------------------------------------------
// P1: n0<768: Wpe_nat[b][k][d] (natural) ; n0>=768: Wbig[b][n][k] (transposed)
// ---------------------------------------------------------------------------
__global__ __launch_bounds__(256) void prep_wct(
    const float* __restrict__ answer, const float* __restrict__ W_p,
    const float* __restrict__ W_t, __hip_bfloat16* __restrict__ Wpe_nat,
    __hip_bfloat16* __restrict__ Wbig)
{
    __shared__ float lds[64][65];
    __shared__ float a_s[64];
    const int n0 = blockIdx.x * 64;
    const int k0 = blockIdx.y * 64;
    const int b  = blockIdx.z;
    const int tid = threadIdx.x;

    if (tid < 64) a_s[tid] = answer[((size_t)b * L_ + (L_ - 1)) * D_ + k0 + tid];
    __syncthreads();

    if (n0 < D_) {
#pragma unroll
        for (int i = 0; i < 16; ++i) {
            int k = (tid >> 6) + i * 4;
            int n = tid & 63;
            float v = W_p[(size_t)(D_ + k0 + k) * D_ + n0 + n] +
                      a_s[k] * W_p[(size_t)(2 * D_ + k0 + k) * D_ + n0 + n];
            Wpe_nat[(size_t)b * D_ * D_ + (size_t)(k0 + k) * D_ + n0 + n] =
                __float2bfloat16(v);
        }
    } else {
        const int nn0 = n0 - D_;
#pragma unroll
        for (int i = 0; i < 16; ++i) {
            int k = (tid >> 6) + i * 4;
            int n = tid & 63;
            lds[k][n] = W_t[(size_t)(D_ + k0 + k) * D_ + nn0 + n] +
                        a_s[k] * W_t[(size_t)(2 * D_ + k0 + k) * D_ + nn0 + n];
        }
        __syncthreads();
#pragma unroll
        for (int j = 0; j < 16; ++j) {
            int n = (tid >> 6) + j * 4;
            int kk = tid & 63;
            Wbig[((size_t)b * NC_ + n0 + n) * D_ + k0 + kk] =
                __float2bfloat16(lds[kk][n]);
        }
    }
}

// ---------------------------------------------------------------------------
// P2: c_p[b][d], c_t[b][d]
// ---------------------------------------------------------------------------
__global__ __launch_bounds__(512) void prep_const(
    const float* __restrict__ answer,
    const float* __restrict__ W_p, const float* __restrict__ b_p,
    const float* __restrict__ W_t, const float* __restrict__ b_t,
    float* __restrict__ c_p, float* __restrict__ c_t)
{
    const int b = blockIdx.x;
    const int d = blockIdx.y * 64 + (threadIdx.x & 63);
    const int ks = threadIdx.x >> 6;
    const float* a = answer + ((size_t)b * L_ + (L_ - 1)) * D_;
    float sp = 0.f, st = 0.f;
#pragma unroll 4
    for (int k = ks; k < D_; k += 8) {
        float av = a[k];
        sp += av * W_p[(size_t)k * D_ + d];
        st += av * W_t[(size_t)k * D_ + d];
    }
    __shared__ float red[2][8][64];
    red[0][ks][threadIdx.x & 63] = sp;
    red[1][ks][threadIdx.x & 63] = st;
    __syncthreads();
    if (ks == 0) {
        float s1 = b_p[d], s2 = b_t[d];
#pragma unroll
        for (int i = 0; i < 8; ++i) {
            s1 += red[0][i][threadIdx.x & 63];
            s2 += red[1][i][threadIdx.x & 63];
        }
        c_p[b * D_ + d] = s1;
        c_t[b * D_ + d] = s2;
    }
}

// ---------------------------------------------------------------------------
// P2b: cc[b][n] = b1[n] + sum_d c_p[b][d]*W1[d][n]
// ---------------------------------------------------------------------------
__global__ __launch_bounds__(512) void prep_cc(
    const float* __restrict__ c_p, const float* __restrict__ W1,
    const float* __restrict__ b1, float* __restrict__ cc)
{
    const int b = blockIdx.x;
    const int n = blockIdx.y * 64 + (threadIdx.x & 63);
    const int ks = threadIdx.x >> 6;
    float s = 0.f;
#pragma unroll 4
    for (int d = ks; d < D_; d += 8)
        s += c_p[b * D_ + d] * W1[(size_t)d * D_ + n];
    __shared__ float red[8][64];
    red[ks][threadIdx.x & 63] = s;
    __syncthreads();
    if (ks == 0) {
        float tot = b1[n];
#pragma unroll
        for (int i = 0; i < 8; ++i) tot += red[i][threadIdx.x & 63];
        cc[b * D_ + n] = tot;
    }
}

// ---------------------------------------------------------------------------
// P3: q slice (L-1) fp32 -> bf16  (reinstated: proven faster than fused fp32-A)
// ---------------------------------------------------------------------------
__global__ __launch_bounds__(256) void conv_q(
    const float* __restrict__ q, __hip_bfloat16* __restrict__ qb)
{
    size_t base = ((size_t)blockIdx.x * 256 + threadIdx.x) * 4;
    int b = (int)(base / ((size_t)T_ * D_));
    size_t off = base % ((size_t)T_ * D_);
    float4 v = *reinterpret_cast<const float4*>(
        &q[((size_t)b * L_ + (L_ - 1)) * (size_t)T_ * D_ + off]);
    ushort4 o;
    o.x = f2bf(v.x); o.y = f2bf(v.y); o.z = f2bf(v.z); o.w = f2bf(v.w);
    *reinterpret_cast<ushort4*>(&qb[base]) = o;
}

// ---------------------------------------------------------------------------
// P4: W1 -> W1at[n][k]=W1[k][n] (k<768), W1bt[n][k]=W1[768+k][n]
// ---------------------------------------------------------------------------
__global__ __launch_bounds__(256) void prep_w1t(
    const float* __restrict__ W1, __hip_bfloat16* __restrict__ W1at,
    __hip_bfloat16* __restrict__ W1bt)
{
    __shared__ float lds[64][65];
    const int n0 = blockIdx.x * 64;
    const int k0 = blockIdx.y * 64;
    const int tid = threadIdx.x;
#pragma unroll
    for (int i = 0; i < 16; ++i) {
        int k = (tid >> 6) + i * 4;
        int n = tid & 63;
        lds[k][n] = W1[(size_t)(k0 + k) * D_ + n0 + n];
    }
    __syncthreads();
    __hip_bfloat16* dst = (k0 < D_) ? W1at : W1bt;
    const int kk0 = (k0 < D_) ? k0 : k0 - D_;
#pragma unroll
    for (int j = 0; j < 16; ++j) {
        int n = (tid >> 6) + j * 4;
        int kk = tid & 63;
        dst[(size_t)(n0 + n) * D_ + kk0 + kk] = __float2bfloat16(lds[kk][n]);
    }
}

// ---------------------------------------------------------------------------
// P5: parallel group lists (order-unstable OK; segment op is max)
// ---------------------------------------------------------------------------
__global__ __launch_bounds__(256) void build_groups(
    const int* __restrict__ tids, int* __restrict__ glist, int* __restrict__ goff)
{
    __shared__ int cnt[B_][G_];
    __shared__ int off[B_][G_ + 1];
    __shared__ int cur[B_][G_];
    const int tid = threadIdx.x;

    if (tid < B_ * G_) cnt[tid / G_][tid % G_] = 0;
    __syncthreads();
    for (int i = tid; i < B_ * P_; i += 256)
        atomicAdd(&cnt[i / P_][tids[i]], 1);
    __syncthreads();
    if (tid < B_) {
        int o = 0;
        for (int g = 0; g < G_; ++g) { off[tid][g] = o; o += cnt[tid][g]; }
        off[tid][G_] = o;
        for (int g = 0; g <= G_; ++g) goff[tid * (G_ + 1) + g] = off[tid][g];
    }
    __syncthreads();
    if (tid < B_ * G_) cur[tid / G_][tid % G_] = off[tid / G_][tid % G_];
    __syncthreads();
    for (int i = tid; i < B_ * P_; i += 256) {
        int b = i / P_, p = i % P_;
        int slot = atomicAdd(&cur[b][tids[i]], 1);
        glist[b * P_ + slot] = p;
    }
}

// ---------------------------------------------------------------------------
// K1: Wbig[b] lower half:  Wbig[b][j][k] = sum_d W1at[j][d] * Wpe_nat[b][k][d]
// ---------------------------------------------------------------------------
__global__ __launch_bounds__(256) void gemm_c1(
    const __hip_bfloat16* __restrict__ W1at,
    const __hip_bfloat16* __restrict__ Wpe_nat,
    __hip_bfloat16* __restrict__ Wbig)
{
    const int tm = blockIdx.x, tn = blockIdx.y, b = blockIdx.z;
    __shared__ __align__(16) __hip_bfloat16 As[128][64];
    __shared__ __align__(16) __hip_bfloat16 Bs[128][64];

    const int tid = threadIdx.x;
    const int lane = tid & 63, w = tid >> 6;
    const int wm = w & 1, wn = w >> 1;

    f32x4 acc[4][4];
#pragma unroll
    for (int i = 0; i < 4; ++i)
#pragma unroll
        for (int j = 0; j < 4; ++j)
#pragma unroll
            for (int e = 0; e < 4; ++e) acc[i][j][e] = 0.0f;

    mfma_loop64(W1at + (size_t)tm * 128 * D_,
                Wpe_nat + (size_t)b * D_ * D_ + (size_t)tn * 128 * D_,
                As, Bs, lane, w, wm, wn, acc);

#pragma unroll
    for (int mi = 0; mi < 4; ++mi)
#pragma unroll
        for (int ni = 0; ni < 4; ++ni) {
            int col = tn * 128 + wn * 64 + ni * 16 + (lane & 15);
            int row = tm * 128 + wm * 64 + mi * 16 + (lane >> 4) * 4;
#pragma unroll
            for (int e = 0; e < 4; ++e)
                Wbig[(size_t)b * NC_ * D_ + (size_t)(row + e) * D_ + col] =
                    __float2bfloat16(acc[mi][ni][e]);
        }
}

// ---------------------------------------------------------------------------
// K2: ts = qb @ Wbig[b][768..1536]^T + c_t   (M=6400, N=768, K=768)
// ---------------------------------------------------------------------------
__global__ __launch_bounds__(256) void gemm_ts(
    const __hip_bfloat16* __restrict__ qb, const __hip_bfloat16* __restrict__ Wbig,
    const float* __restrict__ c_t, __hip_bfloat16* __restrict__ ts)
{
    const int tm = blockIdx.x, tn = blockIdx.y, b = blockIdx.z;
    __shared__ __align__(16) __hip_bfloat16 As[128][64];
    __shared__ __align__(16) __hip_bfloat16 Bs[128][64];

    const int tid = threadIdx.x;
    const int lane = tid & 63, w = tid >> 6;
    const int wm = w & 1, wn = w >> 1;

    f32x4 acc[4][4];
#pragma unroll
    for (int i = 0; i < 4; ++i)
#pragma unroll
        for (int j = 0; j < 4; ++j)
#pragma unroll
            for (int e = 0; e < 4; ++e) acc[i][j][e] = 0.0f;

    mfma_loop64(qb + (size_t)b * T_ * D_ + (size_t)tm * 128 * D_,
                Wbig + (size_t)b * NC_ * D_ + (size_t)(D_ + tn * 128) * D_,
                As, Bs, lane, w, wm, wn, acc);

#pragma unroll
    for (int mi = 0; mi < 4; ++mi)
#pragma unroll
        for (int ni = 0; ni < 4; ++ni) {
            int col = tn * 128 + wn * 64 + ni * 16 + (lane & 15);
            int rb  = tm * 128 + wm * 64 + mi * 16 + (lane >> 4) * 4;
            float cv = c_t[b * D_ + col];
#pragma unroll
            for (int e = 0; e < 4; ++e)
                ts[((size_t)b * T_ + rb + e) * D_ + col] =
                    __float2bfloat16(acc[mi][ni][e] + cv);
        }
}

// ---------------------------------------------------------------------------
// K3: segment max via group lists; 4 d's per thread
// ---------------------------------------------------------------------------
__global__ __launch_bounds__(256) void segmax_kernel(
    const __hip_bfloat16* __restrict__ ts, const int* __restrict__ glist,
    const int* __restrict__ goff, __hip_bfloat16* __restrict__ sm)
{
    int idx = blockIdx.x * 256 + threadIdx.x;
    int d4 = idx % (D_ / 4);
    int bt = idx / (D_ / 4);
    int t = bt % TPP_;
    int b = bt / TPP_;

    const ushort4* base =
        reinterpret_cast<const ushort4*>(ts + ((size_t)b * T_ + t) * D_) + d4;

    for (int g = 0; g < G_; ++g) {
        float m0 = -1e30f, m1 = -1e30f, m2 = -1e30f, m3 = -1e30f;
        int i0 = goff[b * (G_ + 1) + g], i1 = goff[b * (G_ + 1) + g + 1];
        for (int i = i0; i < i1; ++i) {
            int p = glist[b * P_ + i];
            ushort4 u = base[(size_t)p * TPP_ * (D_ / 4)];
            m0 = fmaxf(m0, bfu2f(u.x));
            m1 = fmaxf(m1, bfu2f(u.y));
            m2 = fmaxf(m2, bfu2f(u.z));
            m3 = fmaxf(m3, bfu2f(u.w));
        }
        ushort4 o;
        o.x = f2bf(m0); o.y = f2bf(m1); o.z = f2bf(m2); o.w = f2bf(m3);
        reinterpret_cast<ushort4*>(
            sm + (((size_t)b * G_ + g) * TPP_ + t) * D_)[d4] = o;
    }
}

// ---------------------------------------------------------------------------
// K4: smW = sm @ W1bt^T   (M=2560, N=768, K=768)
// ---------------------------------------------------------------------------
__global__ __launch_bounds__(256) void gemm_smw(
    const __hip_bfloat16* __restrict__ sm, const __hip_bfloat16* __restrict__ W1bt,
    __hip_bfloat16* __restrict__ smW)
{
    const int tm = blockIdx.x, tn = blockIdx.y;
    __shared__ __align__(16) __hip_bfloat16 As[128][64];
    __shared__ __align__(16) __hip_bfloat16 Bs[128][64];

    const int tid = threadIdx.x;
    const int lane = tid & 63, w = tid >> 6;
    const int wm = w & 1, wn = w >> 1;

    f32x4 acc[4][4];
#pragma unroll
    for (int i = 0; i < 4; ++i)
#pragma unroll
        for (int j = 0; j < 4; ++j)
#pragma unroll
            for (int e = 0; e < 4; ++e) acc[i][j][e] = 0.0f;

    mfma_loop64(sm + (size_t)tm * 128 * D_,
                W1bt + (size_t)tn * 128 * D_,
                As, Bs, lane, w, wm, wn, acc);

#pragma unroll
    for (int mi = 0; mi < 4; ++mi)
#pragma unroll
        for (int ni = 0; ni < 4; ++ni) {
            int col = tn * 128 + wn * 64 + ni * 16 + (lane & 15);
            int rb  = tm * 128 + wm * 64 + mi * 16 + (lane >> 4) * 4;
#pragma unroll
            for (int e = 0; e < 4; ++e)
                smW[(size_t)(rb + e) * D_ + col] = __float2bfloat16(acc[mi][ni][e]);
        }
}

// ---------------------------------------------------------------------------
// K5a: out[bp] = b2 * sum_t mask[bp][t]
// ---------------------------------------------------------------------------
__global__ __launch_bounds__(256) void out_init(
    const float* __restrict__ mask, const float* __restrict__ b2,
    float* __restrict__ out)
{
    int bp = blockIdx.x * 256 + threadIdx.x;
    if (bp >= B_ * P_) return;
    float s = 0.f;
#pragma unroll 8
    for (int t = 0; t < TPP_; ++t) s += mask[(size_t)bp * TPP_ + t];
    out[bp] = s * b2[0];
}

// ---------------------------------------------------------------------------
// K5: fused  acc = qb @ Wbig[b][0..768]^T ; v = relu(acc + cc + smW[g])
//     rowdot = v . W2 ; out[b][p] += sum_t mask * rowdot   (psW never stored)
// ---------------------------------------------------------------------------
__global__ __launch_bounds__(256) void gemm_fin(
    const __hip_bfloat16* __restrict__ qb, const __hip_bfloat16* __restrict__ Wbig,
    const float* __restrict__ cc, const __hip_bfloat16* __restrict__ smW,
    const int* __restrict__ tids, const float* __restrict__ W2,
    const float* __restrict__ mask, float* __restrict__ out)
{
    const int tm = blockIdx.x, tn = blockIdx.y, b = blockIdx.z;
    __shared__ __align__(16) __hip_bfloat16 As[128][64];
    __shared__ __align__(16) __hip_bfloat16 Bs[128][64];
    __shared__ float rowsum[2][128];

    const int tid = threadIdx.x;
    const int lane = tid & 63, w = tid >> 6;
    const int wm = w & 1, wn = w >> 1;

    f32x4 acc[4][4];
#pragma unroll
    for (int i = 0; i < 4; ++i)
#pragma unroll
        for (int j = 0; j < 4; ++j)
#pragma unroll
            for (int e = 0; e < 4; ++e) acc[i][j][e] = 0.0f;

    mfma_loop64(qb + (size_t)b * T_ * D_ + (size_t)tm * 128 * D_,
                Wbig + (size_t)b * NC_ * D_ + (size_t)tn * 128 * D_,
                As, Bs, lane, w, wm, wn, acc);

    // ---- fused epilogue (validated in r3): relu(acc+cc+smW).W2, mask-sum ----
    const int p = tm * 2 + wm;
    const int g = tids[b * P_ + p];
    const __hip_bfloat16* smWg = smW + ((size_t)(b * G_ + g) * TPP_) * D_;
    const int h = lane >> 4;

    float rs[4][4];
#pragma unroll
    for (int mi = 0; mi < 4; ++mi)
#pragma unroll
        for (int e = 0; e < 4; ++e) rs[mi][e] = 0.f;

#pragma unroll
    for (int ni = 0; ni < 4; ++ni) {
        int col = tn * 128 + wn * 64 + ni * 16 + (lane & 15);
        float ccv = cc[b * D_ + col];
        float w2v = W2[col];
#pragma unroll
        for (int mi = 0; mi < 4; ++mi)
#pragma unroll
            for (int e = 0; e < 4; ++e) {
                int trow = mi * 16 + h * 4 + e;   // row within passage
                float v = acc[mi][ni][e] + ccv +
                          bfu2f(*reinterpret_cast<const unsigned short*>(
                              &smWg[(size_t)trow * D_ + col]));
                rs[mi][e] += fmaxf(v, 0.f) * w2v;
            }
    }
#pragma unroll
    for (int off = 8; off >= 1; off >>= 1)
#pragma unroll
        for (int mi = 0; mi < 4; ++mi)
#pragma unroll
            for (int e = 0; e < 4; ++e) rs[mi][e] += __shfl_xor(rs[mi][e], off);

    if ((lane & 15) == 0) {
#pragma unroll
        for (int mi = 0; mi < 4; ++mi)
#pragma unroll
            for (int e = 0; e < 4; ++e)
                rowsum[wn][wm * 64 + mi * 16 + h * 4 + e] = rs[mi][e];
    }
    __syncthreads();

    if (tid < 128) {
        int pp = tid >> 6, t = tid & 63;
        float v = (rowsum[0][tid] + rowsum[1][tid]) *
                  mask[((size_t)b * P_ + tm * 2 + pp) * TPP_ + t];
#pragma unroll
        for (int off = 32; off >= 1; off >>= 1) v += __shfl_xor(v, off);
        if (t == 0) atomicAdd(&out[b * P_ + tm * 2 + pp], v);
    }
}

// ---------------------------------------------------------------------------
extern "C" void kernel_launch(void* const* d_in, const int* in_sizes, int n_in,
                              void* d_out, int out_size, void* d_ws, size_t ws_size,
                              hipStream_t stream)
{
    const float* answer = (const float*)d_in[0];
    const float* qps    = (const float*)d_in[1];
    const float* mask   = (const float*)d_in[2];
    const int*   tids   = (const int*)d_in[3];
    // d_in[4] = fusion_scores: unused by the reference
    const float* W_p = (const float*)d_in[5];
    const float* b_p = (const float*)d_in[6];
    const float* W_t = (const float*)d_in[7];
    const float* b_t = (const float*)d_in[8];
    const float* W1  = (const float*)d_in[9];
    const float* b1  = (const float*)d_in[10];
    const float* W2  = (const float*)d_in[11];
    const float* b2  = (const float*)d_in[12];
    float* out = (float*)d_out;

    char* ws = (char*)d_ws;
    __hip_bfloat16* Wpe_nat = (__hip_bfloat16*)ws; ws += (size_t)B_ * D_ * D_ * 2;
    __hip_bfloat16* Wbig    = (__hip_bfloat16*)ws; ws += (size_t)B_ * NC_ * D_ * 2;
    float* c_p = (float*)ws;                   ws += (size_t)B_ * D_ * 4;
    float* c_t = (float*)ws;                   ws += (size_t)B_ * D_ * 4;
    float* cc  = (float*)ws;                   ws += (size_t)B_ * D_ * 4;
    __hip_bfloat16* qb = (__hip_bfloat16*)ws;  ws += (size_t)B_ * T_ * D_ * 2;
    __hip_bfloat16* ts = (__hip_bfloat16*)ws;  ws += (size_t)B_ * T_ * D_ * 2;
    __hip_bfloat16* sm = (__hip_bfloat16*)ws;  ws += (size_t)B_ * G_ * TPP_ * D_ * 2;
    __hip_bfloat16* smW = (__hip_bfloat16*)ws; ws += (size_t)B_ * G_ * TPP_ * D_ * 2;
    __hip_bfloat16* W1at = (__hip_bfloat16*)ws; ws += (size_t)D_ * D_ * 2;
    __hip_bfloat16* W1bt = (__hip_bfloat16*)ws; ws += (size_t)D_ * D_ * 2;
    int* glist = (int*)ws;                     ws += B_ * P_ * 4;
    int* goff  = (int*)ws;                     ws += B_ * (G_ + 1) * 4;

    prep_wct<<<dim3(NC_ / 64, D_ / 64, B_), 256, 0, stream>>>(
        answer, W_p, W_t, Wpe_nat, Wbig);
    prep_const<<<dim3(B_, D_ / 64), 512, 0, stream>>>(
        answer, W_p, b_p, W_t, b_t, c_p, c_t);
    prep_cc<<<dim3(B_, D_ / 64), 512, 0, stream>>>(c_p, W1, b1, cc);
    conv_q<<<(B_ * T_ * D_) / (256 * 4), 256, 0, stream>>>(qps, qb);
    prep_w1t<<<dim3(D_ / 64, NC_ / 64), 256, 0, stream>>>(W1, W1at, W1bt);
    build_groups<<<1, 256, 0, stream>>>(tids, glist, goff);
    gemm_c1<<<dim3(D_ / 128, D_ / 128, B_), 256, 0, stream>>>(W1at, Wpe_nat, Wbig);
    gemm_ts<<<dim3(T_ / 128, D_ / 128, B_), 256, 0, stream>>>(qb, Wbig, c_t, ts);
    segmax_kernel<<<(B_ * TPP_ * (D_ / 4)) / 256, 256, 0, stream>>>(
        ts, glist, goff, sm);
    gemm_smw<<<dim3((B_ * G_ * TPP_) / 128, D_ / 128), 256, 0, stream>>>(
        sm, W1bt, smW);
    out_init<<<(B_ * P_ + 255) / 256, 256, 0, stream>>>(mask, b2, out);
    gemm_fin<<<dim3(T_ / 128, D_ / 128, B_), 256, 0, stream>>>(
        qb, Wbig, cc, smW, tids, W2, mask, out);
}

// Round 7
// 246.017 us; speedup vs baseline: 1.4036x; 1.0498x over previous
//
#include <hip/hip_runtime.h>
#include <hip/hip_bf16.h>

#define B_ 4
#define L_ 2
#define P_ 100
#define TPP_ 64
#define D_ 768
#define G_ 10
#define T_ (P_ * TPP_)   // 6400
#define NC_ (2 * D_)     // 1536

typedef __attribute__((ext_vector_type(8))) short bf16x8;
typedef __attribute__((ext_vector_type(4))) float f32x4;

__device__ __forceinline__ unsigned short f2bf(float f) {
    __hip_bfloat16 h = __float2bfloat16(f);
    return *reinterpret_cast<unsigned short*>(&h);
}
__device__ __forceinline__ float bfu2f(unsigned short u) {
    return __uint_as_float(((unsigned int)u) << 16);
}

__device__ __forceinline__ void gload_lds16(const void* g, void* l) {
    __builtin_amdgcn_global_load_lds(
        (const __attribute__((address_space(1))) void*)g,
        (__attribute__((address_space(3))) void*)l, 16, 0, 0);
}

// ---------------------------------------------------------------------------
// BK=64 staged chunk + both-sides 8x16B-slot swizzle (validated r6):
//   LDS[r][s] = G[r][s ^ (r&7)]; reader uses s = gs ^ (r&7).
// r7 change: DOUBLE-BUFFERED with NAMED buffers (rule #20: no runtime buffer
// index). stage(t+1) is issued BEFORE compute(t), so global-load latency
// hides under the 16 ds_read + 32 MFMA phase; one vmcnt-draining barrier
// per K-tile (catalog T3 minimum-2-phase recipe).
// ---------------------------------------------------------------------------
__device__ __forceinline__ void stage64(
    const __hip_bfloat16* __restrict__ Ag, const __hip_bfloat16* __restrict__ Bg,
    int k0, __hip_bfloat16 (*As)[64], __hip_bfloat16 (*Bs)[64],
    int w, int row_l, int soff)
{
#pragma unroll
    for (int j = 0; j < 4; ++j) {
        int r = w * 32 + j * 8 + row_l;   // r&7 == row_l
        gload_lds16(Ag + (size_t)r * D_ + k0 + soff, &As[w * 32 + j * 8][0]);
        gload_lds16(Bg + (size_t)r * D_ + k0 + soff, &Bs[w * 32 + j * 8][0]);
    }
}

__device__ __forceinline__ void mfma_step64(
    __hip_bfloat16 (*As)[64], __hip_bfloat16 (*Bs)[64],
    int rr, int h, int wm, int wn, f32x4 acc[4][4])
{
#pragma unroll
    for (int ks = 0; ks < 2; ++ks) {
        const int rsl = (((ks << 2) + h) ^ (rr & 7)) << 3;
        bf16x8 af[4], bfr[4];
#pragma unroll
        for (int mi = 0; mi < 4; ++mi)
            af[mi] = *reinterpret_cast<const bf16x8*>(
                &As[wm * 64 + mi * 16 + rr][rsl]);
#pragma unroll
        for (int ni = 0; ni < 4; ++ni)
            bfr[ni] = *reinterpret_cast<const bf16x8*>(
                &Bs[wn * 64 + ni * 16 + rr][rsl]);
#pragma unroll
        for (int mi = 0; mi < 4; ++mi)
#pragma unroll
            for (int ni = 0; ni < 4; ++ni)
                acc[mi][ni] = __builtin_amdgcn_mfma_f32_16x16x32_bf16(
                    af[mi], bfr[ni], acc[mi][ni], 0, 0, 0);
    }
}

// Double-buffered main loop over K=768 (12 BK=64 tiles, 6 macro-iters).
#define MFMA_LOOP_DB(Ag, Bg)                                                  \
    {                                                                         \
        const int rr = lane & 15, h = lane >> 4;                              \
        const int row_l = lane >> 3;                                          \
        const int soff = ((lane & 7) ^ row_l) << 3;                           \
        stage64((Ag), (Bg), 0, As0, Bs0, w, row_l, soff);                     \
        __syncthreads();                                                      \
        for (int k0 = 0; k0 < D_; k0 += 128) {                                \
            if (k0 + 64 < D_)                                                 \
                stage64((Ag), (Bg), k0 + 64, As1, Bs1, w, row_l, soff);       \
            mfma_step64(As0, Bs0, rr, h, wm, wn, acc);                        \
            __syncthreads();                                                  \
            if (k0 + 128 < D_)                                                \
                stage64((Ag), (Bg), k0 + 128, As0, Bs0, w, row_l, soff);      \
            mfma_step64(As1, Bs1, rr, h, wm, wn, acc);                        \
            __syncthreads();                                                  \
        }                                                                     \
    }

#define DECL_LDS_DB()                                                         \
    __shared__ __align__(16) __hip_bfloat16 As0[128][64];                     \
    __shared__ __align__(16) __hip_bfloat16 Bs0[128][64];                     \
    __shared__ __align__(16) __hip_bfloat16 As1[128][64];                     \
    __shared__ __align__(16) __hip_bfloat16 Bs1[128][64];

#define DECL_ACC()                                                            \
    f32x4 acc[4][4];                                                          \
    _Pragma("unroll") for (int i = 0; i < 4; ++i)                             \
        _Pragma("unroll") for (int j = 0; j < 4; ++j)                         \
            _Pragma("unroll") for (int e = 0; e < 4; ++e) acc[i][j][e] = 0.0f;

// ---------------------------------------------------------------------------
// P1: n0<768: Wpe_nat[b][k][d] (natural) ; n0>=768: Wbig[b][n][k] (transposed)
// ---------------------------------------------------------------------------
__global__ __launch_bounds__(256) void prep_wct(
    const float* __restrict__ answer, const float* __restrict__ W_p,
    const float* __restrict__ W_t, __hip_bfloat16* __restrict__ Wpe_nat,
    __hip_bfloat16* __restrict__ Wbig)
{
    __shared__ float lds[64][65];
    __shared__ float a_s[64];
    const int n0 = blockIdx.x * 64;
    const int k0 = blockIdx.y * 64;
    const int b  = blockIdx.z;
    const int tid = threadIdx.x;

    if (tid < 64) a_s[tid] = answer[((size_t)b * L_ + (L_ - 1)) * D_ + k0 + tid];
    __syncthreads();

    if (n0 < D_) {
#pragma unroll
        for (int i = 0; i < 16; ++i) {
            int k = (tid >> 6) + i * 4;
            int n = tid & 63;
            float v = W_p[(size_t)(D_ + k0 + k) * D_ + n0 + n] +
                      a_s[k] * W_p[(size_t)(2 * D_ + k0 + k) * D_ + n0 + n];
            Wpe_nat[(size_t)b * D_ * D_ + (size_t)(k0 + k) * D_ + n0 + n] =
                __float2bfloat16(v);
        }
    } else {
        const int nn0 = n0 - D_;
#pragma unroll
        for (int i = 0; i < 16; ++i) {
            int k = (tid >> 6) + i * 4;
            int n = tid & 63;
            lds[k][n] = W_t[(size_t)(D_ + k0 + k) * D_ + nn0 + n] +
                        a_s[k] * W_t[(size_t)(2 * D_ + k0 + k) * D_ + nn0 + n];
        }
        __syncthreads();
#pragma unroll
        for (int j = 0; j < 16; ++j) {
            int n = (tid >> 6) + j * 4;
            int kk = tid & 63;
            Wbig[((size_t)b * NC_ + n0 + n) * D_ + k0 + kk] =
                __float2bfloat16(lds[kk][n]);
        }
    }
}

// ---------------------------------------------------------------------------
// P2: c_p[b][d], c_t[b][d]
// ---------------------------------------------------------------------------
__global__ __launch_bounds__(512) void prep_const(
    const float* __restrict__ answer,
    const float* __restrict__ W_p, const float* __restrict__ b_p,
    const float* __restrict__ W_t, const float* __restrict__ b_t,
    float* __restrict__ c_p, float* __restrict__ c_t)
{
    const int b = blockIdx.x;
    const int d = blockIdx.y * 64 + (threadIdx.x & 63);
    const int ks = threadIdx.x >> 6;
    const float* a = answer + ((size_t)b * L_ + (L_ - 1)) * D_;
    float sp = 0.f, st = 0.f;
#pragma unroll 4
    for (int k = ks; k < D_; k += 8) {
        float av = a[k];
        sp += av * W_p[(size_t)k * D_ + d];
        st += av * W_t[(size_t)k * D_ + d];
    }
    __shared__ float red[2][8][64];
    red[0][ks][threadIdx.x & 63] = sp;
    red[1][ks][threadIdx.x & 63] = st;
    __syncthreads();
    if (ks == 0) {
        float s1 = b_p[d], s2 = b_t[d];
#pragma unroll
        for (int i = 0; i < 8; ++i) {
            s1 += red[0][i][threadIdx.x & 63];
            s2 += red[1][i][threadIdx.x & 63];
        }
        c_p[b * D_ + d] = s1;
        c_t[b * D_ + d] = s2;
    }
}

// ---------------------------------------------------------------------------
// P2b: cc[b][n] = b1[n] + sum_d c_p[b][d]*W1[d][n]
// ---------------------------------------------------------------------------
__global__ __launch_bounds__(512) void prep_cc(
    const float* __restrict__ c_p, const float* __restrict__ W1,
    const float* __restrict__ b1, float* __restrict__ cc)
{
    const int b = blockIdx.x;
    const int n = blockIdx.y * 64 + (threadIdx.x & 63);
    const int ks = threadIdx.x >> 6;
    float s = 0.f;
#pragma unroll 4
    for (int d = ks; d < D_; d += 8)
        s += c_p[b * D_ + d] * W1[(size_t)d * D_ + n];
    __shared__ float red[8][64];
    red[ks][threadIdx.x & 63] = s;
    __syncthreads();
    if (ks == 0) {
        float tot = b1[n];
#pragma unroll
        for (int i = 0; i < 8; ++i) tot += red[i][threadIdx.x & 63];
        cc[b * D_ + n] = tot;
    }
}

// ---------------------------------------------------------------------------
// P3: q slice (L-1) fp32 -> bf16, 8 elem/thread
// ---------------------------------------------------------------------------
__global__ __launch_bounds__(256) void conv_q(
    const float* __restrict__ q, __hip_bfloat16* __restrict__ qb)
{
    size_t base = ((size_t)blockIdx.x * 256 + threadIdx.x) * 8;   // < B*T*D exact
    int b = (int)(base / ((size_t)T_ * D_));
    size_t off = base % ((size_t)T_ * D_);
    const float4* src = reinterpret_cast<const float4*>(
        q + ((size_t)b * L_ + (L_ - 1)) * (size_t)T_ * D_ + off);
    float4 v0 = src[0], v1 = src[1];
    bf16x8 o;
    o[0] = (short)f2bf(v0.x); o[1] = (short)f2bf(v0.y);
    o[2] = (short)f2bf(v0.z); o[3] = (short)f2bf(v0.w);
    o[4] = (short)f2bf(v1.x); o[5] = (short)f2bf(v1.y);
    o[6] = (short)f2bf(v1.z); o[7] = (short)f2bf(v1.w);
    *reinterpret_cast<bf16x8*>(&qb[base]) = o;
}

// ---------------------------------------------------------------------------
// P4: W1 -> W1at[n][k]=W1[k][n] (k<768), W1bt[n][k]=W1[768+k][n]
// ---------------------------------------------------------------------------
__global__ __launch_bounds__(256) void prep_w1t(
    const float* __restrict__ W1, __hip_bfloat16* __restrict__ W1at,
    __hip_bfloat16* __restrict__ W1bt)
{
    __shared__ float lds[64][65];
    const int n0 = blockIdx.x * 64;
    const int k0 = blockIdx.y * 64;
    const int tid = threadIdx.x;
#pragma unroll
    for (int i = 0; i < 16; ++i) {
        int k = (tid >> 6) + i * 4;
        int n = tid & 63;
        lds[k][n] = W1[(size_t)(k0 + k) * D_ + n0 + n];
    }
    __syncthreads();
    __hip_bfloat16* dst = (k0 < D_) ? W1at : W1bt;
    const int kk0 = (k0 < D_) ? k0 : k0 - D_;
#pragma unroll
    for (int j = 0; j < 16; ++j) {
        int n = (tid >> 6) + j * 4;
        int kk = tid & 63;
        dst[(size_t)(n0 + n) * D_ + kk0 + kk] = __float2bfloat16(lds[kk][n]);
    }
}

// ---------------------------------------------------------------------------
// P5: parallel group lists (order-unstable OK; segment op is max)
// ---------------------------------------------------------------------------
__global__ __launch_bounds__(256) void build_groups(
    const int* __restrict__ tids, int* __restrict__ glist, int* __restrict__ goff)
{
    __shared__ int cnt[B_][G_];
    __shared__ int off[B_][G_ + 1];
    __shared__ int cur[B_][G_];
    const int tid = threadIdx.x;

    if (tid < B_ * G_) cnt[tid / G_][tid % G_] = 0;
    __syncthreads();
    for (int i = tid; i < B_ * P_; i += 256)
        atomicAdd(&cnt[i / P_][tids[i]], 1);
    __syncthreads();
    if (tid < B_) {
        int o = 0;
        for (int g = 0; g < G_; ++g) { off[tid][g] = o; o += cnt[tid][g]; }
        off[tid][G_] = o;
        for (int g = 0; g <= G_; ++g) goff[tid * (G_ + 1) + g] = off[tid][g];
    }
    __syncthreads();
    if (tid < B_ * G_) cur[tid / G_][tid % G_] = off[tid / G_][tid % G_];
    __syncthreads();
    for (int i = tid; i < B_ * P_; i += 256) {
        int b = i / P_, p = i % P_;
        int slot = atomicAdd(&cur[b][tids[i]], 1);
        glist[b * P_ + slot] = p;
    }
}

// ---------------------------------------------------------------------------
// K1: Wbig[b] lower half:  Wbig[b][j][k] = sum_d W1at[j][d] * Wpe_nat[b][k][d]
// ---------------------------------------------------------------------------
__global__ __launch_bounds__(256) void gemm_c1(
    const __hip_bfloat16* __restrict__ W1at,
    const __hip_bfloat16* __restrict__ Wpe_nat,
    __hip_bfloat16* __restrict__ Wbig)
{
    const int tm = blockIdx.x, tn = blockIdx.y, b = blockIdx.z;
    DECL_LDS_DB();
    const int tid = threadIdx.x;
    const int lane = tid & 63, w = tid >> 6;
    const int wm = w & 1, wn = w >> 1;
    DECL_ACC();

    const __hip_bfloat16* Ag = W1at + (size_t)tm * 128 * D_;
    const __hip_bfloat16* Bg = Wpe_nat + (size_t)b * D_ * D_ + (size_t)tn * 128 * D_;
    MFMA_LOOP_DB(Ag, Bg);

#pragma unroll
    for (int mi = 0; mi < 4; ++mi)
#pragma unroll
        for (int ni = 0; ni < 4; ++ni) {
            int col = tn * 128 + wn * 64 + ni * 16 + (lane & 15);
            int row = tm * 128 + wm * 64 + mi * 16 + (lane >> 4) * 4;
#pragma unroll
            for (int e = 0; e < 4; ++e)
                Wbig[(size_t)b * NC_ * D_ + (size_t)(row + e) * D_ + col] =
                    __float2bfloat16(acc[mi][ni][e]);
        }
}

// ---------------------------------------------------------------------------
// K2: ts = qb @ Wbig[b][768..1536]^T + c_t   (M=6400, N=768, K=768)
// ---------------------------------------------------------------------------
__global__ __launch_bounds__(256) void gemm_ts(
    const __hip_bfloat16* __restrict__ qb, const __hip_bfloat16* __restrict__ Wbig,
    const float* __restrict__ c_t, __hip_bfloat16* __restrict__ ts)
{
    const int tm = blockIdx.x, tn = blockIdx.y, b = blockIdx.z;
    DECL_LDS_DB();
    const int tid = threadIdx.x;
    const int lane = tid & 63, w = tid >> 6;
    const int wm = w & 1, wn = w >> 1;
    DECL_ACC();

    const __hip_bfloat16* Ag = qb + (size_t)b * T_ * D_ + (size_t)tm * 128 * D_;
    const __hip_bfloat16* Bg = Wbig + (size_t)b * NC_ * D_ + (size_t)(D_ + tn * 128) * D_;
    MFMA_LOOP_DB(Ag, Bg);

#pragma unroll
    for (int mi = 0; mi < 4; ++mi)
#pragma unroll
        for (int ni = 0; ni < 4; ++ni) {
            int col = tn * 128 + wn * 64 + ni * 16 + (lane & 15);
            int rb  = tm * 128 + wm * 64 + mi * 16 + (lane >> 4) * 4;
            float cv = c_t[b * D_ + col];
#pragma unroll
            for (int e = 0; e < 4; ++e)
                ts[((size_t)b * T_ + rb + e) * D_ + col] =
                    __float2bfloat16(acc[mi][ni][e] + cv);
        }
}

// ---------------------------------------------------------------------------
// K3: segment max via group lists; 4 d's per thread
// ---------------------------------------------------------------------------
__global__ __launch_bounds__(256) void segmax_kernel(
    const __hip_bfloat16* __restrict__ ts, const int* __restrict__ glist,
    const int* __restrict__ goff, __hip_bfloat16* __restrict__ sm)
{
    int idx = blockIdx.x * 256 + threadIdx.x;
    int d4 = idx % (D_ / 4);
    int bt = idx / (D_ / 4);
    int t = bt % TPP_;
    int b = bt / TPP_;

    const ushort4* base =
        reinterpret_cast<const ushort4*>(ts + ((size_t)b * T_ + t) * D_) + d4;

    for (int g = 0; g < G_; ++g) {
        float m0 = -1e30f, m1 = -1e30f, m2 = -1e30f, m3 = -1e30f;
        int i0 = goff[b * (G_ + 1) + g], i1 = goff[b * (G_ + 1) + g + 1];
        for (int i = i0; i < i1; ++i) {
            int p = glist[b * P_ + i];
            ushort4 u = base[(size_t)p * TPP_ * (D_ / 4)];
            m0 = fmaxf(m0, bfu2f(u.x));
            m1 = fmaxf(m1, bfu2f(u.y));
            m2 = fmaxf(m2, bfu2f(u.z));
            m3 = fmaxf(m3, bfu2f(u.w));
        }
        ushort4 o;
        o.x = f2bf(m0); o.y = f2bf(m1); o.z = f2bf(m2); o.w = f2bf(m3);
        reinterpret_cast<ushort4*>(
            sm + (((size_t)b * G_ + g) * TPP_ + t) * D_)[d4] = o;
    }
}

// ---------------------------------------------------------------------------
// K4: smW = sm @ W1bt^T   (M=2560, N=768, K=768)
// ---------------------------------------------------------------------------
__global__ __launch_bounds__(256) void gemm_smw(
    const __hip_bfloat16* __restrict__ sm, const __hip_bfloat16* __restrict__ W1bt,
    __hip_bfloat16* __restrict__ smW)
{
    const int tm = blockIdx.x, tn = blockIdx.y;
    DECL_LDS_DB();
    const int tid = threadIdx.x;
    const int lane = tid & 63, w = tid >> 6;
    const int wm = w & 1, wn = w >> 1;
    DECL_ACC();

    const __hip_bfloat16* Ag = sm + (size_t)tm * 128 * D_;
    const __hip_bfloat16* Bg = W1bt + (size_t)tn * 128 * D_;
    MFMA_LOOP_DB(Ag, Bg);

#pragma unroll
    for (int mi = 0; mi < 4; ++mi)
#pragma unroll
        for (int ni = 0; ni < 4; ++ni) {
            int col = tn * 128 + wn * 64 + ni * 16 + (lane & 15);
            int rb  = tm * 128 + wm * 64 + mi * 16 + (lane >> 4) * 4;
#pragma unroll
            for (int e = 0; e < 4; ++e)
                smW[(size_t)(rb + e) * D_ + col] = __float2bfloat16(acc[mi][ni][e]);
        }
}

// ---------------------------------------------------------------------------
// K5a: out[bp] = b2 * sum_t mask[bp][t]
// ---------------------------------------------------------------------------
__global__ __launch_bounds__(256) void out_init(
    const float* __restrict__ mask, const float* __restrict__ b2,
    float* __restrict__ out)
{
    int bp = blockIdx.x * 256 + threadIdx.x;
    if (bp >= B_ * P_) return;
    float s = 0.f;
#pragma unroll 8
    for (int t = 0; t < TPP_; ++t) s += mask[(size_t)bp * TPP_ + t];
    out[bp] = s * b2[0];
}

// ---------------------------------------------------------------------------
// K5: fused  acc = qb @ Wbig[b][0..768]^T ; v = relu(acc + cc + smW[g])
//     rowdot = v . W2 ; out[b][p] += sum_t mask * rowdot
// ---------------------------------------------------------------------------
__global__ __launch_bounds__(256) void gemm_fin(
    const __hip_bfloat16* __restrict__ qb, const __hip_bfloat16* __restrict__ Wbig,
    const float* __restrict__ cc, const __hip_bfloat16* __restrict__ smW,
    const int* __restrict__ tids, const float* __restrict__ W2,
    const float* __restrict__ mask, float* __restrict__ out)
{
    const int tm = blockIdx.x, tn = blockIdx.y, b = blockIdx.z;
    DECL_LDS_DB();
    __shared__ float rowsum[2][128];

    const int tid = threadIdx.x;
    const int lane = tid & 63, w = tid >> 6;
    const int wm = w & 1, wn = w >> 1;
    DECL_ACC();

    const __hip_bfloat16* Ag = qb + (size_t)b * T_ * D_ + (size_t)tm * 128 * D_;
    const __hip_bfloat16* Bg = Wbig + (size_t)b * NC_ * D_ + (size_t)tn * 128 * D_;
    MFMA_LOOP_DB(Ag, Bg);

    // ---- fused epilogue (validated r3/r6): relu(acc+cc+smW).W2, mask-sum ----
    const int p = tm * 2 + wm;
    const int g = tids[b * P_ + p];
    const __hip_bfloat16* smWg = smW + ((size_t)(b * G_ + g) * TPP_) * D_;
    const int h = lane >> 4;

    float rs[4][4];
#pragma unroll
    for (int mi = 0; mi < 4; ++mi)
#pragma unroll
        for (int e = 0; e < 4; ++e) rs[mi][e] = 0.f;

#pragma unroll
    for (int ni = 0; ni < 4; ++ni) {
        int col = tn * 128 + wn * 64 + ni * 16 + (lane & 15);
        float ccv = cc[b * D_ + col];
        float w2v = W2[col];
#pragma unroll
        for (int mi = 0; mi < 4; ++mi)
#pragma unroll
            for (int e = 0; e < 4; ++e) {
                int trow = mi * 16 + h * 4 + e;
                float v = acc[mi][ni][e] + ccv +
                          bfu2f(*reinterpret_cast<const unsigned short*>(
                              &smWg[(size_t)trow * D_ + col]));
                rs[mi][e] += fmaxf(v, 0.f) * w2v;
            }
    }
#pragma unroll
    for (int off = 8; off >= 1; off >>= 1)
#pragma unroll
        for (int mi = 0; mi < 4; ++mi)
#pragma unroll
            for (int e = 0; e < 4; ++e) rs[mi][e] += __shfl_xor(rs[mi][e], off);

    if ((lane & 15) == 0) {
#pragma unroll
        for (int mi = 0; mi < 4; ++mi)
#pragma unroll
            for (int e = 0; e < 4; ++e)
                rowsum[wn][wm * 64 + mi * 16 + h * 4 + e] = rs[mi][e];
    }
    __syncthreads();

    if (tid < 128) {
        int pp = tid >> 6, t = tid & 63;
        float v = (rowsum[0][tid] + rowsum[1][tid]) *
                  mask[((size_t)b * P_ + tm * 2 + pp) * TPP_ + t];
#pragma unroll
        for (int off = 32; off >= 1; off >>= 1) v += __shfl_xor(v, off);
        if (t == 0) atomicAdd(&out[b * P_ + tm * 2 + pp], v);
    }
}

// ---------------------------------------------------------------------------
extern "C" void kernel_launch(void* const* d_in, const int* in_sizes, int n_in,
                              void* d_out, int out_size, void* d_ws, size_t ws_size,
                              hipStream_t stream)
{
    const float* answer = (const float*)d_in[0];
    const float* qps    = (const float*)d_in[1];
    const float* mask   = (const float*)d_in[2];
    const int*   tids   = (const int*)d_in[3];
    // d_in[4] = fusion_scores: unused by the reference
    const float* W_p = (const float*)d_in[5];
    const float* b_p = (const float*)d_in[6];
    const float* W_t = (const float*)d_in[7];
    const float* b_t = (const float*)d_in[8];
    const float* W1  = (const float*)d_in[9];
    const float* b1  = (const float*)d_in[10];
    const float* W2  = (const float*)d_in[11];
    const float* b2  = (const float*)d_in[12];
    float* out = (float*)d_out;

    char* ws = (char*)d_ws;
    __hip_bfloat16* Wpe_nat = (__hip_bfloat16*)ws; ws += (size_t)B_ * D_ * D_ * 2;
    __hip_bfloat16* Wbig    = (__hip_bfloat16*)ws; ws += (size_t)B_ * NC_ * D_ * 2;
    float* c_p = (float*)ws;                   ws += (size_t)B_ * D_ * 4;
    float* c_t = (float*)ws;                   ws += (size_t)B_ * D_ * 4;
    float* cc  = (float*)ws;                   ws += (size_t)B_ * D_ * 4;
    __hip_bfloat16* qb = (__hip_bfloat16*)ws;  ws += (size_t)B_ * T_ * D_ * 2;
    __hip_bfloat16* ts = (__hip_bfloat16*)ws;  ws += (size_t)B_ * T_ * D_ * 2;
    __hip_bfloat16* sm = (__hip_bfloat16*)ws;  ws += (size_t)B_ * G_ * TPP_ * D_ * 2;
    __hip_bfloat16* smW = (__hip_bfloat16*)ws; ws += (size_t)B_ * G_ * TPP_ * D_ * 2;
    __hip_bfloat16* W1at = (__hip_bfloat16*)ws; ws += (size_t)D_ * D_ * 2;
    __hip_bfloat16* W1bt = (__hip_bfloat16*)ws; ws += (size_t)D_ * D_ * 2;
    int* glist = (int*)ws;                     ws += B_ * P_ * 4;
    int* goff  = (int*)ws;                     ws += B_ * (G_ + 1) * 4;

    prep_wct<<<dim3(NC_ / 64, D_ / 64, B_), 256, 0, stream>>>(
        answer, W_p, W_t, Wpe_nat, Wbig);
    prep_const<<<dim3(B_, D_ / 64), 512, 0, stream>>>(
        answer, W_p, b_p, W_t, b_t, c_p, c_t);
    prep_cc<<<dim3(B_, D_ / 64), 512, 0, stream>>>(c_p, W1, b1, cc);
    conv_q<<<(B_ * T_ * D_) / (256 * 8), 256, 0, stream>>>(qps, qb);
    prep_w1t<<<dim3(D_ / 64, NC_ / 64), 256, 0, stream>>>(W1, W1at, W1bt);
    build_groups<<<1, 256, 0, stream>>>(tids, glist, goff);
    gemm_c1<<<dim3(D_ / 128, D_ / 128, B_), 256, 0, stream>>>(W1at, Wpe_nat, Wbig);
    gemm_ts<<<dim3(T_ / 128, D_ / 128, B_), 256, 0, stream>>>(qb, Wbig, c_t, ts);
    segmax_kernel<<<(B_ * TPP_ * (D_ / 4)) / 256, 256, 0, stream>>>(
        ts, glist, goff, sm);
    gemm_smw<<<dim3((B_ * G_ * TPP_) / 128, D_ / 128), 256, 0, stream>>>(
        sm, W1bt, smW);
    out_init<<<(B_ * P_ + 255) / 256, 256, 0, stream>>>(mask, b2, out);
    gemm_fin<<<dim3(T_ / 128, D_ / 128, B_), 256, 0, stream>>>(
        qb, Wbig, cc, smW, tids, W2, mask, out);
}

// Round 8
// 245.888 us; speedup vs baseline: 1.4043x; 1.0005x over previous
//
#include <hip/hip_runtime.h>
#include <hip/hip_bf16.h>

#define B_ 4
#define L_ 2
#define P_ 100
#define TPP_ 64
#define D_ 768
#define G_ 10
#define T_ (P_ * TPP_)   // 6400
#define NC_ (2 * D_)     // 1536

typedef __attribute__((ext_vector_type(8))) short bf16x8;
typedef __attribute__((ext_vector_type(4))) float f32x4;

__device__ __forceinline__ unsigned short f2bf(float f) {
    __hip_bfloat16 h = __float2bfloat16(f);
    return *reinterpret_cast<unsigned short*>(&h);
}
__device__ __forceinline__ float bfu2f(unsigned short u) {
    return __uint_as_float(((unsigned int)u) << 16);
}

__device__ __forceinline__ void gload_lds16(const void* g, void* l) {
    __builtin_amdgcn_global_load_lds(
        (const __attribute__((address_space(1))) void*)g,
        (__attribute__((address_space(3))) void*)l, 16, 0, 0);
}

// ---------------------------------------------------------------------------
// BK=64 staged chunk + both-sides 8x16B-slot swizzle (validated r6):
//   LDS[r][s] = G[r][s ^ (r&7)]; reader uses s = gs ^ (r&7).
// r7 change: DOUBLE-BUFFERED with NAMED buffers (rule #20: no runtime buffer
// index). stage(t+1) is issued BEFORE compute(t), so global-load latency
// hides under the 16 ds_read + 32 MFMA phase; one vmcnt-draining barrier
// per K-tile (catalog T3 minimum-2-phase recipe).
// ---------------------------------------------------------------------------
__device__ __forceinline__ void stage64(
    const __hip_bfloat16* __restrict__ Ag, const __hip_bfloat16* __restrict__ Bg,
    int k0, __hip_bfloat16 (*As)[64], __hip_bfloat16 (*Bs)[64],
    int w, int row_l, int soff)
{
#pragma unroll
    for (int j = 0; j < 4; ++j) {
        int r = w * 32 + j * 8 + row_l;   // r&7 == row_l
        gload_lds16(Ag + (size_t)r * D_ + k0 + soff, &As[w * 32 + j * 8][0]);
        gload_lds16(Bg + (size_t)r * D_ + k0 + soff, &Bs[w * 32 + j * 8][0]);
    }
}

__device__ __forceinline__ void mfma_step64(
    __hip_bfloat16 (*As)[64], __hip_bfloat16 (*Bs)[64],
    int rr, int h, int wm, int wn, f32x4 acc[4][4])
{
#pragma unroll
    for (int ks = 0; ks < 2; ++ks) {
        const int rsl = (((ks << 2) + h) ^ (rr & 7)) << 3;
        bf16x8 af[4], bfr[4];
#pragma unroll
        for (int mi = 0; mi < 4; ++mi)
            af[mi] = *reinterpret_cast<const bf16x8*>(
                &As[wm * 64 + mi * 16 + rr][rsl]);
#pragma unroll
        for (int ni = 0; ni < 4; ++ni)
            bfr[ni] = *reinterpret_cast<const bf16x8*>(
                &Bs[wn * 64 + ni * 16 + rr][rsl]);
#pragma unroll
        for (int mi = 0; mi < 4; ++mi)
#pragma unroll
            for (int ni = 0; ni < 4; ++ni)
                acc[mi][ni] = __builtin_amdgcn_mfma_f32_16x16x32_bf16(
                    af[mi], bfr[ni], acc[mi][ni], 0, 0, 0);
    }
}

// Double-buffered main loop over K=768 (12 BK=64 tiles, 6 macro-iters).
#define MFMA_LOOP_DB(Ag, Bg)                                                  \
    {                                                                         \
        const int rr = lane & 15, h = lane >> 4;                              \
        const int row_l = lane >> 3;                                          \
        const int soff = ((lane & 7) ^ row_l) << 3;                           \
        stage64((Ag), (Bg), 0, As0, Bs0, w, row_l, soff);                     \
        __syncthreads();                                                      \
        for (int k0 = 0; k0 < D_; k0 += 128) {                                \
            if (k0 + 64 < D_)                                                 \
                stage64((Ag), (Bg), k0 + 64, As1, Bs1, w, row_l, soff);       \
            mfma_step64(As0, Bs0, rr, h, wm, wn, acc);                        \
            __syncthreads();                                                  \
            if (k0 + 128 < D_)                                                \
                stage64((Ag), (Bg), k0 + 128, As0, Bs0, w, row_l, soff);      \
            mfma_step64(As1, Bs1, rr, h, wm, wn, acc);                        \
            __syncthreads();                                                  \
        }                                                                     \
    }

#define DECL_LDS_DB()                                                         \
    __shared__ __align__(16) __hip_bfloat16 As0[128][64];                     \
    __shared__ __align__(16) __hip_bfloat16 Bs0[128][64];                     \
    __shared__ __align__(16) __hip_bfloat16 As1[128][64];                     \
    __shared__ __align__(16) __hip_bfloat16 Bs1[128][64];

#define DECL_ACC()                                                            \
    f32x4 acc[4][4];                                                          \
    _Pragma("unroll") for (int i = 0; i < 4; ++i)                             \
        _Pragma("unroll") for (int j = 0; j < 4; ++j)                         \
            _Pragma("unroll") for (int e = 0; e < 4; ++e) acc[i][j][e] = 0.0f;

// ---------------------------------------------------------------------------
// P1: n0<768: Wpe_nat[b][k][d] (natural) ; n0>=768: Wbig[b][n][k] (transposed)
// ---------------------------------------------------------------------------
__global__ __launch_bounds__(256) void prep_wct(
    const float* __restrict__ answer, const float* __restrict__ W_p,
    const float* __restrict__ W_t, __hip_bfloat16* __restrict__ Wpe_nat,
    __hip_bfloat16* __restrict__ Wbig)
{
    __shared__ float lds[64][65];
    __shared__ float a_s[64];
    const int n0 = blockIdx.x * 64;
    const int k0 = blockIdx.y * 64;
    const int b  = blockIdx.z;
    const int tid = threadIdx.x;

    if (tid < 64) a_s[tid] = answer[((size_t)b * L_ + (L_ - 1)) * D_ + k0 + tid];
    __syncthreads();

    if (n0 < D_) {
#pragma unroll
        for (int i = 0; i < 16; ++i) {
            int k = (tid >> 6) + i * 4;
            int n = tid & 63;
            float v = W_p[(size_t)(D_ + k0 + k) * D_ + n0 + n] +
                      a_s[k] * W_p[(size_t)(2 * D_ + k0 + k) * D_ + n0 + n];
            Wpe_nat[(size_t)b * D_ * D_ + (size_t)(k0 + k) * D_ + n0 + n] =
                __float2bfloat16(v);
        }
    } else {
        const int nn0 = n0 - D_;
#pragma unroll
        for (int i = 0; i < 16; ++i) {
            int k = (tid >> 6) + i * 4;
            int n = tid & 63;
            lds[k][n] = W_t[(size_t)(D_ + k0 + k) * D_ + nn0 + n] +
                        a_s[k] * W_t[(size_t)(2 * D_ + k0 + k) * D_ + nn0 + n];
        }
        __syncthreads();
#pragma unroll
        for (int j = 0; j < 16; ++j) {
            int n = (tid >> 6) + j * 4;
            int kk = tid & 63;
            Wbig[((size_t)b * NC_ + n0 + n) * D_ + k0 + kk] =
                __float2bfloat16(lds[kk][n]);
        }
    }
}

// ---------------------------------------------------------------------------
// P2: c_p[b][d], c_t[b][d]
// ---------------------------------------------------------------------------
__global__ __launch_bounds__(512) void prep_const(
    const float* __restrict__ answer,
    const float* __restrict__ W_p, const float* __restrict__ b_p,
    const float* __restrict__ W_t, const float* __restrict__ b_t,
    float* __restrict__ c_p, float* __restrict__ c_t)
{
    const int b = blockIdx.x;
    const int d = blockIdx.y * 64 + (threadIdx.x & 63);
    const int ks = threadIdx.x >> 6;
    const float* a = answer + ((size_t)b * L_ + (L_ - 1)) * D_;
    float sp = 0.f, st = 0.f;
#pragma unroll 4
    for (int k = ks; k < D_; k += 8) {
        float av = a[k];
        sp += av * W_p[(size_t)k * D_ + d];
        st += av * W_t[(size_t)k * D_ + d];
    }
    __shared__ float red[2][8][64];
    red[0][ks][threadIdx.x & 63] = sp;
    red[1][ks][threadIdx.x & 63] = st;
    __syncthreads();
    if (ks == 0) {
        float s1 = b_p[d], s2 = b_t[d];
#pragma unroll
        for (int i = 0; i < 8; ++i) {
            s1 += red[0][i][threadIdx.x & 63];
            s2 += red[1][i][threadIdx.x & 63];
        }
        c_p[b * D_ + d] = s1;
        c_t[b * D_ + d] = s2;
    }
}

// ---------------------------------------------------------------------------
// P2b: cc[b][n] = b1[n] + sum_d c_p[b][d]*W1[d][n]
// ---------------------------------------------------------------------------
__global__ __launch_bounds__(512) void prep_cc(
    const float* __restrict__ c_p, const float* __restrict__ W1,
    const float* __restrict__ b1, float* __restrict__ cc)
{
    const int b = blockIdx.x;
    const int n = blockIdx.y * 64 + (threadIdx.x & 63);
    const int ks = threadIdx.x >> 6;
    float s = 0.f;
#pragma unroll 4
    for (int d = ks; d < D_; d += 8)
        s += c_p[b * D_ + d] * W1[(size_t)d * D_ + n];
    __shared__ float red[8][64];
    red[ks][threadIdx.x & 63] = s;
    __syncthreads();
    if (ks == 0) {
        float tot = b1[n];
#pragma unroll
        for (int i = 0; i < 8; ++i) tot += red[i][threadIdx.x & 63];
        cc[b * D_ + n] = tot;
    }
}

// ---------------------------------------------------------------------------
// P3: q slice (L-1) fp32 -> bf16, 8 elem/thread
// ---------------------------------------------------------------------------
__global__ __launch_bounds__(256) void conv_q(
    const float* __restrict__ q, __hip_bfloat16* __restrict__ qb)
{
    size_t base = ((size_t)blockIdx.x * 256 + threadIdx.x) * 8;   // < B*T*D exact
    int b = (int)(base / ((size_t)T_ * D_));
    size_t off = base % ((size_t)T_ * D_);
    const float4* src = reinterpret_cast<const float4*>(
        q + ((size_t)b * L_ + (L_ - 1)) * (size_t)T_ * D_ + off);
    float4 v0 = src[0], v1 = src[1];
    bf16x8 o;
    o[0] = (short)f2bf(v0.x); o[1] = (short)f2bf(v0.y);
    o[2] = (short)f2bf(v0.z); o[3] = (short)f2bf(v0.w);
    o[4] = (short)f2bf(v1.x); o[5] = (short)f2bf(v1.y);
    o[6] = (short)f2bf(v1.z); o[7] = (short)f2bf(v1.w);
    *reinterpret_cast<bf16x8*>(&qb[base]) = o;
}

// ---------------------------------------------------------------------------
// P4: W1 -> W1at[n][k]=W1[k][n] (k<768), W1bt[n][k]=W1[768+k][n]
// ---------------------------------------------------------------------------
__global__ __launch_bounds__(256) void prep_w1t(
    const float* __restrict__ W1, __hip_bfloat16* __restrict__ W1at,
    __hip_bfloat16* __restrict__ W1bt)
{
    __shared__ float lds[64][65];
    const int n0 = blockIdx.x * 64;
    const int k0 = blockIdx.y * 64;
    const int tid = threadIdx.x;
#pragma unroll
    for (int i = 0; i < 16; ++i) {
        int k = (tid >> 6) + i * 4;
        int n = tid & 63;
        lds[k][n] = W1[(size_t)(k0 + k) * D_ + n0 + n];
    }
    __syncthreads();
    __hip_bfloat16* dst = (k0 < D_) ? W1at : W1bt;
    const int kk0 = (k0 < D_) ? k0 : k0 - D_;
#pragma unroll
    for (int j = 0; j < 16; ++j) {
        int n = (tid >> 6) + j * 4;
        int kk = tid & 63;
        dst[(size_t)(n0 + n) * D_ + kk0 + kk] = __float2bfloat16(lds[kk][n]);
    }
}

// ---------------------------------------------------------------------------
// P5: parallel group lists (order-unstable OK; segment op is max)
// ---------------------------------------------------------------------------
__global__ __launch_bounds__(256) void build_groups(
    const int* __restrict__ tids, int* __restrict__ glist, int* __restrict__ goff)
{
    __shared__ int cnt[B_][G_];
    __shared__ int off[B_][G_ + 1];
    __shared__ int cur[B_][G_];
    const int tid = threadIdx.x;

    if (tid < B_ * G_) cnt[tid / G_][tid % G_] = 0;
    __syncthreads();
    for (int i = tid; i < B_ * P_; i += 256)
        atomicAdd(&cnt[i / P_][tids[i]], 1);
    __syncthreads();
    if (tid < B_) {
        int o = 0;
        for (int g = 0; g < G_; ++g) { off[tid][g] = o; o += cnt[tid][g]; }
        off[tid][G_] = o;
        for (int g = 0; g <= G_; ++g) goff[tid * (G_ + 1) + g] = off[tid][g];
    }
    __syncthreads();
    if (tid < B_ * G_) cur[tid / G_][tid % G_] = off[tid / G_][tid % G_];
    __syncthreads();
    for (int i = tid; i < B_ * P_; i += 256) {
        int b = i / P_, p = i % P_;
        int slot = atomicAdd(&cur[b][tids[i]], 1);
        glist[b * P_ + slot] = p;
    }
}

// ---------------------------------------------------------------------------
// K1: Wbig[b] lower half:  Wbig[b][j][k] = sum_d W1at[j][d] * Wpe_nat[b][k][d]
// ---------------------------------------------------------------------------
__global__ __launch_bounds__(256) void gemm_c1(
    const __hip_bfloat16* __restrict__ W1at,
    const __hip_bfloat16* __restrict__ Wpe_nat,
    __hip_bfloat16* __restrict__ Wbig)
{
    const int tm = blockIdx.x, tn = blockIdx.y, b = blockIdx.z;
    DECL_LDS_DB();
    const int tid = threadIdx.x;
    const int lane = tid & 63, w = tid >> 6;
    const int wm = w & 1, wn = w >> 1;
    DECL_ACC();

    const __hip_bfloat16* Ag = W1at + (size_t)tm * 128 * D_;
    const __hip_bfloat16* Bg = Wpe_nat + (size_t)b * D_ * D_ + (size_t)tn * 128 * D_;
    MFMA_LOOP_DB(Ag, Bg);

#pragma unroll
    for (int mi = 0; mi < 4; ++mi)
#pragma unroll
        for (int ni = 0; ni < 4; ++ni) {
            int col = tn * 128 + wn * 64 + ni * 16 + (lane & 15);
            int row = tm * 128 + wm * 64 + mi * 16 + (lane >> 4) * 4;
#pragma unroll
            for (int e = 0; e < 4; ++e)
                Wbig[(size_t)b * NC_ * D_ + (size_t)(row + e) * D_ + col] =
                    __float2bfloat16(acc[mi][ni][e]);
        }
}

// ---------------------------------------------------------------------------
// K2: ts = qb @ Wbig[b][768..1536]^T + c_t   (M=6400, N=768, K=768)
// ---------------------------------------------------------------------------
__global__ __launch_bounds__(256) void gemm_ts(
    const __hip_bfloat16* __restrict__ qb, const __hip_bfloat16* __restrict__ Wbig,
    const float* __restrict__ c_t, __hip_bfloat16* __restrict__ ts)
{
    const int tm = blockIdx.x, tn = blockIdx.y, b = blockIdx.z;
    DECL_LDS_DB();
    const int tid = threadIdx.x;
    const int lane = tid & 63, w = tid >> 6;
    const int wm = w & 1, wn = w >> 1;
    DECL_ACC();

    const __hip_bfloat16* Ag = qb + (size_t)b * T_ * D_ + (size_t)tm * 128 * D_;
    const __hip_bfloat16* Bg = Wbig + (size_t)b * NC_ * D_ + (size_t)(D_ + tn * 128) * D_;
    MFMA_LOOP_DB(Ag, Bg);

#pragma unroll
    for (int mi = 0; mi < 4; ++mi)
#pragma unroll
        for (int ni = 0; ni < 4; ++ni) {
            int col = tn * 128 + wn * 64 + ni * 16 + (lane & 15);
            int rb  = tm * 128 + wm * 64 + mi * 16 + (lane >> 4) * 4;
            float cv = c_t[b * D_ + col];
#pragma unroll
            for (int e = 0; e < 4; ++e)
                ts[((size_t)b * T_ + rb + e) * D_ + col] =
                    __float2bfloat16(acc[mi][ni][e] + cv);
        }
}

// ---------------------------------------------------------------------------
// K3: segment max via group lists; 4 d's per thread
// ---------------------------------------------------------------------------
__global__ __launch_bounds__(256) void segmax_kernel(
    const __hip_bfloat16* __restrict__ ts, const int* __restrict__ glist,
    const int* __restrict__ goff, __hip_bfloat16* __restrict__ sm)
{
    int idx = blockIdx.x * 256 + threadIdx.x;
    int d4 = idx % (D_ / 4);
    int bt = idx / (D_ / 4);
    int t = bt % TPP_;
    int b = bt / TPP_;

    const ushort4* base =
        reinterpret_cast<const ushort4*>(ts + ((size_t)b * T_ + t) * D_) + d4;

    for (int g = 0; g < G_; ++g) {
        float m0 = -1e30f, m1 = -1e30f, m2 = -1e30f, m3 = -1e30f;
        int i0 = goff[b * (G_ + 1) + g], i1 = goff[b * (G_ + 1) + g + 1];
        for (int i = i0; i < i1; ++i) {
            int p = glist[b * P_ + i];
            ushort4 u = base[(size_t)p * TPP_ * (D_ / 4)];
            m0 = fmaxf(m0, bfu2f(u.x));
            m1 = fmaxf(m1, bfu2f(u.y));
            m2 = fmaxf(m2, bfu2f(u.z));
            m3 = fmaxf(m3, bfu2f(u.w));
        }
        ushort4 o;
        o.x = f2bf(m0); o.y = f2bf(m1); o.z = f2bf(m2); o.w = f2bf(m3);
        reinterpret_cast<ushort4*>(
            sm + (((size_t)b * G_ + g) * TPP_ + t) * D_)[d4] = o;
    }
}

// ---------------------------------------------------------------------------
// K4: smW = sm @ W1bt^T   (M=2560, N=768, K=768)
// ---------------------------------------------------------------------------
__global__ __launch_bounds__(256) void gemm_smw(
    const __hip_bfloat16* __restrict__ sm, const __hip_bfloat16* __restrict__ W1bt,
    __hip_bfloat16* __restrict__ smW)
{
    const int tm = blockIdx.x, tn = blockIdx.y;
    DECL_LDS_DB();
    const int tid = threadIdx.x;
    const int lane = tid & 63, w = tid >> 6;
    const int wm = w & 1, wn = w >> 1;
    DECL_ACC();

    const __hip_bfloat16* Ag = sm + (size_t)tm * 128 * D_;
    const __hip_bfloat16* Bg = W1bt + (size_t)tn * 128 * D_;
    MFMA_LOOP_DB(Ag, Bg);

#pragma unroll
    for (int mi = 0; mi < 4; ++mi)
#pragma unroll
        for (int ni = 0; ni < 4; ++ni) {
            int col = tn * 128 + wn * 64 + ni * 16 + (lane & 15);
            int rb  = tm * 128 + wm * 64 + mi * 16 + (lane >> 4) * 4;
#pragma unroll
            for (int e = 0; e < 4; ++e)
                smW[(size_t)(rb + e) * D_ + col] = __float2bfloat16(acc[mi][ni][e]);
        }
}

// ---------------------------------------------------------------------------
// K5a: out[bp] = b2 * sum_t mask[bp][t]
// ---------------------------------------------------------------------------
__global__ __launch_bounds__(256) void out_init(
    const float* __restrict__ mask, const float* __restrict__ b2,
    float* __restrict__ out)
{
    int bp = blockIdx.x * 256 + threadIdx.x;
    if (bp >= B_ * P_) return;
    float s = 0.f;
#pragma unroll 8
    for (int t = 0; t < TPP_; ++t) s += mask[(size_t)bp * TPP_ + t];
    out[bp] = s * b2[0];
}

// ---------------------------------------------------------------------------
// K5: fused  acc = qb @ Wbig[b][0..768]^T ; v = relu(acc + cc + smW[g])
//     rowdot = v . W2 ; out[b][p] += sum_t mask * rowdot
// ---------------------------------------------------------------------------
__global__ __launch_bounds__(256) void gemm_fin(
    const __hip_bfloat16* __restrict__ qb, const __hip_bfloat16* __restrict__ Wbig,
    const float* __restrict__ cc, const __hip_bfloat16* __restrict__ smW,
    const int* __restrict__ tids, const float* __restrict__ W2,
    const float* __restrict__ mask, float* __restrict__ out)
{
    const int tm = blockIdx.x, tn = blockIdx.y, b = blockIdx.z;
    DECL_LDS_DB();
    __shared__ float rowsum[2][128];

    const int tid = threadIdx.x;
    const int lane = tid & 63, w = tid >> 6;
    const int wm = w & 1, wn = w >> 1;
    DECL_ACC();

    const __hip_bfloat16* Ag = qb + (size_t)b * T_ * D_ + (size_t)tm * 128 * D_;
    const __hip_bfloat16* Bg = Wbig + (size_t)b * NC_ * D_ + (size_t)tn * 128 * D_;
    MFMA_LOOP_DB(Ag, Bg);

    // ---- fused epilogue (validated r3/r6): relu(acc+cc+smW).W2, mask-sum ----
    const int p = tm * 2 + wm;
    const int g = tids[b * P_ + p];
    const __hip_bfloat16* smWg = smW + ((size_t)(b * G_ + g) * TPP_) * D_;
    const int h = lane >> 4;

    float rs[4][4];
#pragma unroll
    for (int mi = 0; mi < 4; ++mi)
#pragma unroll
        for (int e = 0; e < 4; ++e) rs[mi][e] = 0.f;

#pragma unroll
    for (int ni = 0; ni < 4; ++ni) {
        int col = tn * 128 + wn * 64 + ni * 16 + (lane & 15);
        float ccv = cc[b * D_ + col];
        float w2v = W2[col];
#pragma unroll
        for (int mi = 0; mi < 4; ++mi)
#pragma unroll
            for (int e = 0; e < 4; ++e) {
                int trow = mi * 16 + h * 4 + e;
                float v = acc[mi][ni][e] + ccv +
                          bfu2f(*reinterpret_cast<const unsigned short*>(
                              &smWg[(size_t)trow * D_ + col]));
                rs[mi][e] += fmaxf(v, 0.f) * w2v;
            }
    }
#pragma unroll
    for (int off = 8; off >= 1; off >>= 1)
#pragma unroll
        for (int mi = 0; mi < 4; ++mi)
#pragma unroll
            for (int e = 0; e < 4; ++e) rs[mi][e] += __shfl_xor(rs[mi][e], off);

    if ((lane & 15) == 0) {
#pragma unroll
        for (int mi = 0; mi < 4; ++mi)
#pragma unroll
            for (int e = 0; e < 4; ++e)
                rowsum[wn][wm * 64 + mi * 16 + h * 4 + e] = rs[mi][e];
    }
    __syncthreads();

    if (tid < 128) {
        int pp = tid >> 6, t = tid & 63;
        float v = (rowsum[0][tid] + rowsum[1][tid]) *
                  mask[((size_t)b * P_ + tm * 2 + pp) * TPP_ + t];
#pragma unroll
        for (int off = 32; off >= 1; off >>= 1) v += __shfl_xor(v, off);
        if (t == 0) atomicAdd(&out[b * P_ + tm * 2 + pp], v);
    }
}

// ---------------------------------------------------------------------------
extern "C" void kernel_launch(void* const* d_in, const int* in_sizes, int n_in,
                              void* d_out, int out_size, void* d_ws, size_t ws_size,
                              hipStream_t stream)
{
    const float* answer = (const float*)d_in[0];
    const float* qps    = (const float*)d_in[1];
    const float* mask   = (const float*)d_in[2];
    const int*   tids   = (const int*)d_in[3];
    // d_in[4] = fusion_scores: unused by the reference
    const float* W_p = (const float*)d_in[5];
    const float* b_p = (const float*)d_in[6];
    const float* W_t = (const float*)d_in[7];
    const float* b_t = (const float*)d_in[8];
    const float* W1  = (const float*)d_in[9];
    const float* b1  = (const float*)d_in[10];
    const float* W2  = (const float*)d_in[11];
    const float* b2  = (const float*)d_in[12];
    float* out = (float*)d_out;

    char* ws = (char*)d_ws;
    __hip_bfloat16* Wpe_nat = (__hip_bfloat16*)ws; ws += (size_t)B_ * D_ * D_ * 2;
    __hip_bfloat16* Wbig    = (__hip_bfloat16*)ws; ws += (size_t)B_ * NC_ * D_ * 2;
    float* c_p = (float*)ws;                   ws += (size_t)B_ * D_ * 4;
    float* c_t = (float*)ws;                   ws += (size_t)B_ * D_ * 4;
    float* cc  = (float*)ws;                   ws += (size_t)B_ * D_ * 4;
    __hip_bfloat16* qb = (__hip_bfloat16*)ws;  ws += (size_t)B_ * T_ * D_ * 2;
    __hip_bfloat16* ts = (__hip_bfloat16*)ws;  ws += (size_t)B_ * T_ * D_ * 2;
    __hip_bfloat16* sm = (__hip_bfloat16*)ws;  ws += (size_t)B_ * G_ * TPP_ * D_ * 2;
    __hip_bfloat16* smW = (__hip_bfloat16*)ws; ws += (size_t)B_ * G_ * TPP_ * D_ * 2;
    __hip_bfloat16* W1at = (__hip_bfloat16*)ws; ws += (size_t)D_ * D_ * 2;
    __hip_bfloat16* W1bt = (__hip_bfloat16*)ws; ws += (size_t)D_ * D_ * 2;
    int* glist = (int*)ws;                     ws += B_ * P_ * 4;
    int* goff  = (int*)ws;                     ws += B_ * (G_ + 1) * 4;

    prep_wct<<<dim3(NC_ / 64, D_ / 64, B_), 256, 0, stream>>>(
        answer, W_p, W_t, Wpe_nat, Wbig);
    prep_const<<<dim3(B_, D_ / 64), 512, 0, stream>>>(
        answer, W_p, b_p, W_t, b_t, c_p, c_t);
    prep_cc<<<dim3(B_, D_ / 64), 512, 0, stream>>>(c_p, W1, b1, cc);
    conv_q<<<(B_ * T_ * D_) / (256 * 8), 256, 0, stream>>>(qps, qb);
    prep_w1t<<<dim3(D_ / 64, NC_ / 64), 256, 0, stream>>>(W1, W1at, W1bt);
    build_groups<<<1, 256, 0, stream>>>(tids, glist, goff);
    gemm_c1<<<dim3(D_ / 128, D_ / 128, B_), 256, 0, stream>>>(W1at, Wpe_nat, Wbig);
    gemm_ts<<<dim3(T_ / 128, D_ / 128, B_), 256, 0, stream>>>(qb, Wbig, c_t, ts);
    segmax_kernel<<<(B_ * TPP_ * (D_ / 4)) / 256, 256, 0, stream>>>(
        ts, glist, goff, sm);
    gemm_smw<<<dim3((B_ * G_ * TPP_) / 128, D_ / 128), 256, 0, stream>>>(
        sm, W1bt, smW);
    out_init<<<(B_ * P_ + 255) / 256, 256, 0, stream>>>(mask, b2, out);
    gemm_fin<<<dim3(T_ / 128, D_ / 128, B_), 256, 0, stream>>>(
        qb, Wbig, cc, smW, tids, W2, mask, out);
}

// Round 9
// 219.768 us; speedup vs baseline: 1.5713x; 1.1188x over previous
//
#include <hip/hip_runtime.h>
#include <hip/hip_bf16.h>

#define B_ 4
#define L_ 2
#define P_ 100
#define TPP_ 64
#define D_ 768
#define G_ 10
#define T_ (P_ * TPP_)   // 6400
#define NC_ (2 * D_)     // 1536

typedef __attribute__((ext_vector_type(8))) short bf16x8;
typedef __attribute__((ext_vector_type(4))) float f32x4;

__device__ __forceinline__ unsigned short f2bf(float f) {
    __hip_bfloat16 h = __float2bfloat16(f);
    return *reinterpret_cast<unsigned short*>(&h);
}
__device__ __forceinline__ float bfu2f(unsigned short u) {
    return __uint_as_float(((unsigned int)u) << 16);
}

__device__ __forceinline__ void gload_lds16(const void* g, void* l) {
    __builtin_amdgcn_global_load_lds(
        (const __attribute__((address_space(1))) void*)g,
        (__attribute__((address_space(3))) void*)l, 16, 0, 0);
}

#define SBAR()   __builtin_amdgcn_s_barrier()
#define SCHEDB() __builtin_amdgcn_sched_barrier(0)
#define VMCNT8() asm volatile("s_waitcnt vmcnt(8)" ::: "memory")
#define VMCNT0() asm volatile("s_waitcnt vmcnt(0)" ::: "memory")

// ---------------------------------------------------------------------------
// BK=64 stage + both-sides 8x16B-slot swizzle (validated r6/r8):
//   LDS[r][s] = G[r][s ^ (r&7)]; read slot = gs ^ (r&7).
// 8 gload_lds per thread per tile (4 A + 4 B).
// ---------------------------------------------------------------------------
__device__ __forceinline__ void stage64(
    const __hip_bfloat16* __restrict__ Ag, const __hip_bfloat16* __restrict__ Bg,
    int k0, __hip_bfloat16 (*As)[64], __hip_bfloat16 (*Bs)[64],
    int w, int row_l, int soff)
{
#pragma unroll
    for (int j = 0; j < 4; ++j) {
        int r = w * 32 + j * 8 + row_l;   // r&7 == row_l
        gload_lds16(Ag + (size_t)r * D_ + k0 + soff, &As[w * 32 + j * 8][0]);
        gload_lds16(Bg + (size_t)r * D_ + k0 + soff, &Bs[w * 32 + j * 8][0]);
    }
}

__device__ __forceinline__ void mfma_step64(
    __hip_bfloat16 (*As)[64], __hip_bfloat16 (*Bs)[64],
    int rr, int h, int wm, int wn, f32x4 acc[4][4])
{
#pragma unroll
    for (int ks = 0; ks < 2; ++ks) {
        const int rsl = (((ks << 2) + h) ^ (rr & 7)) << 3;
        bf16x8 af[4], bfr[4];
#pragma unroll
        for (int mi = 0; mi < 4; ++mi)
            af[mi] = *reinterpret_cast<const bf16x8*>(
                &As[wm * 64 + mi * 16 + rr][rsl]);
#pragma unroll
        for (int ni = 0; ni < 4; ++ni)
            bfr[ni] = *reinterpret_cast<const bf16x8*>(
                &Bs[wn * 64 + ni * 16 + rr][rsl]);
#pragma unroll
        for (int mi = 0; mi < 4; ++mi)
#pragma unroll
            for (int ni = 0; ni < 4; ++ni)
                acc[mi][ni] = __builtin_amdgcn_mfma_f32_16x16x32_bf16(
                    af[mi], bfr[ni], acc[mi][ni], 0, 0, 0);
    }
}

// ---------------------------------------------------------------------------
// T4 counted-vmcnt pipeline over K=768 (12 BK=64 tiles), named double buffers.
// Per tile: VMCNT(8) waits only THIS tile's 8 loads (next tile's 8 stay in
// flight across the raw s_barrier); second raw barrier before re-staging a
// buffer prevents the r4/m152 overwrite race. No vmcnt(0) until the last tile.
// ---------------------------------------------------------------------------
#define MFMA_LOOP_PIPE(Ag, Bg)                                                \
    {                                                                         \
        const int rr = lane & 15, h = lane >> 4;                              \
        const int row_l = lane >> 3;                                          \
        const int soff = ((lane & 7) ^ row_l) << 3;                           \
        stage64((Ag), (Bg), 0, As0, Bs0, w, row_l, soff);                     \
        stage64((Ag), (Bg), 64, As1, Bs1, w, row_l, soff);                    \
        SCHEDB();                                                             \
        for (int t = 0; t < 10; t += 2) {                                     \
            VMCNT8(); SBAR(); SCHEDB();                                       \
            mfma_step64(As0, Bs0, rr, h, wm, wn, acc);                        \
            SCHEDB(); SBAR(); SCHEDB();                                       \
            stage64((Ag), (Bg), (t + 2) * 64, As0, Bs0, w, row_l, soff);      \
            SCHEDB();                                                         \
            VMCNT8(); SBAR(); SCHEDB();                                       \
            mfma_step64(As1, Bs1, rr, h, wm, wn, acc);                        \
            SCHEDB(); SBAR(); SCHEDB();                                       \
            stage64((Ag), (Bg), (t + 3) * 64, As1, Bs1, w, row_l, soff);      \
            SCHEDB();                                                         \
        }                                                                     \
        VMCNT8(); SBAR(); SCHEDB();                                           \
        mfma_step64(As0, Bs0, rr, h, wm, wn, acc);    /* tile 10 */           \
        SCHEDB();                                                             \
        VMCNT0(); SBAR(); SCHEDB();                                           \
        mfma_step64(As1, Bs1, rr, h, wm, wn, acc);    /* tile 11 */           \
        __syncthreads();                                                      \
    }

#define DECL_LDS_DB()                                                         \
    __shared__ __align__(16) __hip_bfloat16 As0[128][64];                     \
    __shared__ __align__(16) __hip_bfloat16 Bs0[128][64];                     \
    __shared__ __align__(16) __hip_bfloat16 As1[128][64];                     \
    __shared__ __align__(16) __hip_bfloat16 Bs1[128][64];

#define DECL_ACC()                                                            \
    f32x4 acc[4][4];                                                          \
    _Pragma("unroll") for (int i = 0; i < 4; ++i)                             \
        _Pragma("unroll") for (int j = 0; j < 4; ++j)                         \
            _Pragma("unroll") for (int e = 0; e < 4; ++e) acc[i][j][e] = 0.0f;

// ---------------------------------------------------------------------------
// P-ALL: fused independent prep kernels.
//   blocks [0,1152)    : prep_wct   (Wpe_nat / Wbig upper half)
//   blocks [1152,1200) : prep_const (c_p, c_t)                [256-thr rework]
//   blocks [1200,1488) : prep_w1t   (W1at, W1bt)
//   block  1488        : build_groups
//   blocks [1489,1491) : out_init
//   blocks [1491,11091): conv_q     (fp32 -> bf16 q slice)
// ---------------------------------------------------------------------------
__global__ __launch_bounds__(256) void prep_all(
    const float* __restrict__ answer, const float* __restrict__ W_p,
    const float* __restrict__ b_p, const float* __restrict__ W_t,
    const float* __restrict__ b_t, const float* __restrict__ W1,
    const float* __restrict__ qps, const int* __restrict__ tids,
    const float* __restrict__ mask, const float* __restrict__ b2,
    __hip_bfloat16* __restrict__ Wpe_nat, __hip_bfloat16* __restrict__ Wbig,
    float* __restrict__ c_p, float* __restrict__ c_t,
    __hip_bfloat16* __restrict__ qb, __hip_bfloat16* __restrict__ W1at,
    __hip_bfloat16* __restrict__ W1bt, int* __restrict__ glist,
    int* __restrict__ goff, float* __restrict__ out)
{
    __shared__ float lds[64][65];
    __shared__ float a_s[64];
    __shared__ float red2[2][4][64];
    __shared__ int g_cnt[B_][G_];
    __shared__ int g_off[B_][G_ + 1];
    __shared__ int g_cur[B_][G_];

    const int bid = blockIdx.x;
    const int tid = threadIdx.x;

    if (bid < 1152) {
        // ----- prep_wct -----
        const int n0 = (bid % 24) * 64;
        const int k0 = ((bid / 24) % 12) * 64;
        const int b  = bid / 288;
        if (tid < 64) a_s[tid] = answer[((size_t)b * L_ + (L_ - 1)) * D_ + k0 + tid];
        __syncthreads();
        if (n0 < D_) {
#pragma unroll
            for (int i = 0; i < 16; ++i) {
                int k = (tid >> 6) + i * 4;
                int n = tid & 63;
                float v = W_p[(size_t)(D_ + k0 + k) * D_ + n0 + n] +
                          a_s[k] * W_p[(size_t)(2 * D_ + k0 + k) * D_ + n0 + n];
                Wpe_nat[(size_t)b * D_ * D_ + (size_t)(k0 + k) * D_ + n0 + n] =
                    __float2bfloat16(v);
            }
        } else {
            const int nn0 = n0 - D_;
#pragma unroll
            for (int i = 0; i < 16; ++i) {
                int k = (tid >> 6) + i * 4;
                int n = tid & 63;
                lds[k][n] = W_t[(size_t)(D_ + k0 + k) * D_ + nn0 + n] +
                            a_s[k] * W_t[(size_t)(2 * D_ + k0 + k) * D_ + nn0 + n];
            }
            __syncthreads();
#pragma unroll
            for (int j = 0; j < 16; ++j) {
                int n = (tid >> 6) + j * 4;
                int kk = tid & 63;
                Wbig[((size_t)b * NC_ + n0 + n) * D_ + k0 + kk] =
                    __float2bfloat16(lds[kk][n]);
            }
        }
    } else if (bid < 1200) {
        // ----- prep_const (256 threads: 4-way K split) -----
        const int local = bid - 1152;
        const int b = local / 12;
        const int d = (local % 12) * 64 + (tid & 63);
        const int ks = tid >> 6;   // 0..3
        const float* a = answer + ((size_t)b * L_ + (L_ - 1)) * D_;
        float sp = 0.f, st = 0.f;
#pragma unroll 4
        for (int k = ks; k < D_; k += 4) {
            float av = a[k];
            sp += av * W_p[(size_t)k * D_ + d];
            st += av * W_t[(size_t)k * D_ + d];
        }
        red2[0][ks][tid & 63] = sp;
        red2[1][ks][tid & 63] = st;
        __syncthreads();
        if (ks == 0) {
            float s1 = b_p[d], s2 = b_t[d];
#pragma unroll
            for (int i = 0; i < 4; ++i) {
                s1 += red2[0][i][tid & 63];
                s2 += red2[1][i][tid & 63];
            }
            c_p[b * D_ + d] = s1;
            c_t[b * D_ + d] = s2;
        }
    } else if (bid < 1488) {
        // ----- prep_w1t -----
        const int local = bid - 1200;
        const int n0 = (local % 12) * 64;
        const int k0 = (local / 12) * 64;
#pragma unroll
        for (int i = 0; i < 16; ++i) {
            int k = (tid >> 6) + i * 4;
            int n = tid & 63;
            lds[k][n] = W1[(size_t)(k0 + k) * D_ + n0 + n];
        }
        __syncthreads();
        __hip_bfloat16* dst = (k0 < D_) ? W1at : W1bt;
        const int kk0 = (k0 < D_) ? k0 : k0 - D_;
#pragma unroll
        for (int j = 0; j < 16; ++j) {
            int n = (tid >> 6) + j * 4;
            int kk = tid & 63;
            dst[(size_t)(n0 + n) * D_ + kk0 + kk] = __float2bfloat16(lds[kk][n]);
        }
    } else if (bid == 1488) {
        // ----- build_groups -----
        if (tid < B_ * G_) g_cnt[tid / G_][tid % G_] = 0;
        __syncthreads();
        for (int i = tid; i < B_ * P_; i += 256)
            atomicAdd(&g_cnt[i / P_][tids[i]], 1);
        __syncthreads();
        if (tid < B_) {
            int o = 0;
            for (int g = 0; g < G_; ++g) { g_off[tid][g] = o; o += g_cnt[tid][g]; }
            g_off[tid][G_] = o;
            for (int g = 0; g <= G_; ++g) goff[tid * (G_ + 1) + g] = g_off[tid][g];
        }
        __syncthreads();
        if (tid < B_ * G_) g_cur[tid / G_][tid % G_] = g_off[tid / G_][tid % G_];
        __syncthreads();
        for (int i = tid; i < B_ * P_; i += 256) {
            int b = i / P_, p = i % P_;
            int slot = atomicAdd(&g_cur[b][tids[i]], 1);
            glist[b * P_ + slot] = p;
        }
    } else if (bid < 1491) {
        // ----- out_init -----
        int bp = (bid - 1489) * 256 + tid;
        if (bp < B_ * P_) {
            float s = 0.f;
#pragma unroll 8
            for (int t = 0; t < TPP_; ++t) s += mask[(size_t)bp * TPP_ + t];
            out[bp] = s * b2[0];
        }
    } else {
        // ----- conv_q (8 elem/thread) -----
        size_t base = ((size_t)(bid - 1491) * 256 + tid) * 8;
        int b = (int)(base / ((size_t)T_ * D_));
        size_t off = base % ((size_t)T_ * D_);
        const float4* src = reinterpret_cast<const float4*>(
            qps + ((size_t)b * L_ + (L_ - 1)) * (size_t)T_ * D_ + off);
        float4 v0 = src[0], v1 = src[1];
        bf16x8 o;
        o[0] = (short)f2bf(v0.x); o[1] = (short)f2bf(v0.y);
        o[2] = (short)f2bf(v0.z); o[3] = (short)f2bf(v0.w);
        o[4] = (short)f2bf(v1.x); o[5] = (short)f2bf(v1.y);
        o[6] = (short)f2bf(v1.z); o[7] = (short)f2bf(v1.w);
        *reinterpret_cast<bf16x8*>(&qb[base]) = o;
    }
}

// ---------------------------------------------------------------------------
// STAGE2: blocks [0,144) = gemm_c1 (Wbig lower half), [144,192) = prep_cc.
// ---------------------------------------------------------------------------
__global__ __launch_bounds__(256) void stage2(
    const __hip_bfloat16* __restrict__ W1at,
    const __hip_bfloat16* __restrict__ Wpe_nat,
    __hip_bfloat16* __restrict__ Wbig,
    const float* __restrict__ c_p, const float* __restrict__ W1,
    const float* __restrict__ b1, float* __restrict__ cc)
{
    DECL_LDS_DB();
    __shared__ float red[4][64];
    const int bid = blockIdx.x;
    const int tid = threadIdx.x;

    if (bid < 144) {
        const int tm = bid % 6, tn = (bid / 6) % 6, b = bid / 36;
        const int lane = tid & 63, w = tid >> 6;
        const int wm = w & 1, wn = w >> 1;
        DECL_ACC();
        const __hip_bfloat16* Ag = W1at + (size_t)tm * 128 * D_;
        const __hip_bfloat16* Bg =
            Wpe_nat + (size_t)b * D_ * D_ + (size_t)tn * 128 * D_;
        MFMA_LOOP_PIPE(Ag, Bg);
#pragma unroll
        for (int mi = 0; mi < 4; ++mi)
#pragma unroll
            for (int ni = 0; ni < 4; ++ni) {
                int col = tn * 128 + wn * 64 + ni * 16 + (lane & 15);
                int row = tm * 128 + wm * 64 + mi * 16 + (lane >> 4) * 4;
#pragma unroll
                for (int e = 0; e < 4; ++e)
                    Wbig[(size_t)b * NC_ * D_ + (size_t)(row + e) * D_ + col] =
                        __float2bfloat16(acc[mi][ni][e]);
            }
    } else {
        // prep_cc: cc[b][n] = b1[n] + sum_d c_p[b][d]*W1[d][n]
        const int local = bid - 144;
        const int b = local / 12;
        const int n = (local % 12) * 64 + (tid & 63);
        const int ks = tid >> 6;
        float s = 0.f;
#pragma unroll 4
        for (int d = ks; d < D_; d += 4)
            s += c_p[b * D_ + d] * W1[(size_t)d * D_ + n];
        red[ks][tid & 63] = s;
        __syncthreads();
        if (ks == 0) {
            float tot = b1[n];
#pragma unroll
            for (int i = 0; i < 4; ++i) tot += red[i][tid & 63];
            cc[b * D_ + n] = tot;
        }
    }
}

// ---------------------------------------------------------------------------
// K2: ts = qb @ Wbig[b][768..1536]^T + c_t
// ---------------------------------------------------------------------------
__global__ __launch_bounds__(256) void gemm_ts(
    const __hip_bfloat16* __restrict__ qb, const __hip_bfloat16* __restrict__ Wbig,
    const float* __restrict__ c_t, __hip_bfloat16* __restrict__ ts)
{
    const int tm = blockIdx.x, tn = blockIdx.y, b = blockIdx.z;
    DECL_LDS_DB();
    const int tid = threadIdx.x;
    const int lane = tid & 63, w = tid >> 6;
    const int wm = w & 1, wn = w >> 1;
    DECL_ACC();

    const __hip_bfloat16* Ag = qb + (size_t)b * T_ * D_ + (size_t)tm * 128 * D_;
    const __hip_bfloat16* Bg =
        Wbig + (size_t)b * NC_ * D_ + (size_t)(D_ + tn * 128) * D_;
    MFMA_LOOP_PIPE(Ag, Bg);

#pragma unroll
    for (int mi = 0; mi < 4; ++mi)
#pragma unroll
        for (int ni = 0; ni < 4; ++ni) {
            int col = tn * 128 + wn * 64 + ni * 16 + (lane & 15);
            int rb  = tm * 128 + wm * 64 + mi * 16 + (lane >> 4) * 4;
            float cv = c_t[b * D_ + col];
#pragma unroll
            for (int e = 0; e < 4; ++e)
                ts[((size_t)b * T_ + rb + e) * D_ + col] =
                    __float2bfloat16(acc[mi][ni][e] + cv);
        }
}

// ---------------------------------------------------------------------------
// K3: segment max via group lists; 4 d's per thread
// ---------------------------------------------------------------------------
__global__ __launch_bounds__(256) void segmax_kernel(
    const __hip_bfloat16* __restrict__ ts, const int* __restrict__ glist,
    const int* __restrict__ goff, __hip_bfloat16* __restrict__ sm)
{
    int idx = blockIdx.x * 256 + threadIdx.x;
    int d4 = idx % (D_ / 4);
    int bt = idx / (D_ / 4);
    int t = bt % TPP_;
    int b = bt / TPP_;

    const ushort4* base =
        reinterpret_cast<const ushort4*>(ts + ((size_t)b * T_ + t) * D_) + d4;

    for (int g = 0; g < G_; ++g) {
        float m0 = -1e30f, m1 = -1e30f, m2 = -1e30f, m3 = -1e30f;
        int i0 = goff[b * (G_ + 1) + g], i1 = goff[b * (G_ + 1) + g + 1];
        for (int i = i0; i < i1; ++i) {
            int p = glist[b * P_ + i];
            ushort4 u = base[(size_t)p * TPP_ * (D_ / 4)];
            m0 = fmaxf(m0, bfu2f(u.x));
            m1 = fmaxf(m1, bfu2f(u.y));
            m2 = fmaxf(m2, bfu2f(u.z));
            m3 = fmaxf(m3, bfu2f(u.w));
        }
        ushort4 o;
        o.x = f2bf(m0); o.y = f2bf(m1); o.z = f2bf(m2); o.w = f2bf(m3);
        reinterpret_cast<ushort4*>(
            sm + (((size_t)b * G_ + g) * TPP_ + t) * D_)[d4] = o;
    }
}

// ---------------------------------------------------------------------------
// K4: smW = sm @ W1bt^T
// ---------------------------------------------------------------------------
__global__ __launch_bounds__(256) void gemm_smw(
    const __hip_bfloat16* __restrict__ sm, const __hip_bfloat16* __restrict__ W1bt,
    __hip_bfloat16* __restrict__ smW)
{
    const int tm = blockIdx.x, tn = blockIdx.y;
    DECL_LDS_DB();
    const int tid = threadIdx.x;
    const int lane = tid & 63, w = tid >> 6;
    const int wm = w & 1, wn = w >> 1;
    DECL_ACC();

    const __hip_bfloat16* Ag = sm + (size_t)tm * 128 * D_;
    const __hip_bfloat16* Bg = W1bt + (size_t)tn * 128 * D_;
    MFMA_LOOP_PIPE(Ag, Bg);

#pragma unroll
    for (int mi = 0; mi < 4; ++mi)
#pragma unroll
        for (int ni = 0; ni < 4; ++ni) {
            int col = tn * 128 + wn * 64 + ni * 16 + (lane & 15);
            int rb  = tm * 128 + wm * 64 + mi * 16 + (lane >> 4) * 4;
#pragma unroll
            for (int e = 0; e < 4; ++e)
                smW[(size_t)(rb + e) * D_ + col] = __float2bfloat16(acc[mi][ni][e]);
        }
}

// ---------------------------------------------------------------------------
// K5: fused  acc = qb @ Wbig[b][0..768]^T ; v = relu(acc + cc + smW[g])
//     rowdot = v . W2 ; out[b][p] += sum_t mask * rowdot
// ---------------------------------------------------------------------------
__global__ __launch_bounds__(256) void gemm_fin(
    const __hip_bfloat16* __restrict__ qb, const __hip_bfloat16* __restrict__ Wbig,
    const float* __restrict__ cc, const __hip_bfloat16* __restrict__ smW,
    const int* __restrict__ tids, const float* __restrict__ W2,
    const float* __restrict__ mask, float* __restrict__ out)
{
    const int tm = blockIdx.x, tn = blockIdx.y, b = blockIdx.z;
    DECL_LDS_DB();
    __shared__ float rowsum[2][128];

    const int tid = threadIdx.x;
    const int lane = tid & 63, w = tid >> 6;
    const int wm = w & 1, wn = w >> 1;
    DECL_ACC();

    const __hip_bfloat16* Ag = qb + (size_t)b * T_ * D_ + (size_t)tm * 128 * D_;
    const __hip_bfloat16* Bg = Wbig + (size_t)b * NC_ * D_ + (size_t)tn * 128 * D_;
    MFMA_LOOP_PIPE(Ag, Bg);

    const int p = tm * 2 + wm;
    const int g = tids[b * P_ + p];
    const __hip_bfloat16* smWg = smW + ((size_t)(b * G_ + g) * TPP_) * D_;
    const int h = lane >> 4;

    float rs[4][4];
#pragma unroll
    for (int mi = 0; mi < 4; ++mi)
#pragma unroll
        for (int e = 0; e < 4; ++e) rs[mi][e] = 0.f;

#pragma unroll
    for (int ni = 0; ni < 4; ++ni) {
        int col = tn * 128 + wn * 64 + ni * 16 + (lane & 15);
        float ccv = cc[b * D_ + col];
        float w2v = W2[col];
#pragma unroll
        for (int mi = 0; mi < 4; ++mi)
#pragma unroll
            for (int e = 0; e < 4; ++e) {
                int trow = mi * 16 + h * 4 + e;
                float v = acc[mi][ni][e] + ccv +
                          bfu2f(*reinterpret_cast<const unsigned short*>(
                              &smWg[(size_t)trow * D_ + col]));
                rs[mi][e] += fmaxf(v, 0.f) * w2v;
            }
    }
#pragma unroll
    for (int off = 8; off >= 1; off >>= 1)
#pragma unroll
        for (int mi = 0; mi < 4; ++mi)
#pragma unroll
            for (int e = 0; e < 4; ++e) rs[mi][e] += __shfl_xor(rs[mi][e], off);

    if ((lane & 15) == 0) {
#pragma unroll
        for (int mi = 0; mi < 4; ++mi)
#pragma unroll
            for (int e = 0; e < 4; ++e)
                rowsum[wn][wm * 64 + mi * 16 + h * 4 + e] = rs[mi][e];
    }
    __syncthreads();

    if (tid < 128) {
        int pp = tid >> 6, t = tid & 63;
        float v = (rowsum[0][tid] + rowsum[1][tid]) *
                  mask[((size_t)b * P_ + tm * 2 + pp) * TPP_ + t];
#pragma unroll
        for (int off = 32; off >= 1; off >>= 1) v += __shfl_xor(v, off);
        if (t == 0) atomicAdd(&out[b * P_ + tm * 2 + pp], v);
    }
}

// ---------------------------------------------------------------------------
extern "C" void kernel_launch(void* const* d_in, const int* in_sizes, int n_in,
                              void* d_out, int out_size, void* d_ws, size_t ws_size,
                              hipStream_t stream)
{
    const float* answer = (const float*)d_in[0];
    const float* qps    = (const float*)d_in[1];
    const float* mask   = (const float*)d_in[2];
    const int*   tids   = (const int*)d_in[3];
    // d_in[4] = fusion_scores: unused by the reference
    const float* W_p = (const float*)d_in[5];
    const float* b_p = (const float*)d_in[6];
    const float* W_t = (const float*)d_in[7];
    const float* b_t = (const float*)d_in[8];
    const float* W1  = (const float*)d_in[9];
    const float* b1  = (const float*)d_in[10];
    const float* W2  = (const float*)d_in[11];
    const float* b2  = (const float*)d_in[12];
    float* out = (float*)d_out;

    char* ws = (char*)d_ws;
    __hip_bfloat16* Wpe_nat = (__hip_bfloat16*)ws; ws += (size_t)B_ * D_ * D_ * 2;
    __hip_bfloat16* Wbig    = (__hip_bfloat16*)ws; ws += (size_t)B_ * NC_ * D_ * 2;
    float* c_p = (float*)ws;                   ws += (size_t)B_ * D_ * 4;
    float* c_t = (float*)ws;                   ws += (size_t)B_ * D_ * 4;
    float* cc  = (float*)ws;                   ws += (size_t)B_ * D_ * 4;
    __hip_bfloat16* qb = (__hip_bfloat16*)ws;  ws += (size_t)B_ * T_ * D_ * 2;
    __hip_bfloat16* ts = (__hip_bfloat16*)ws;  ws += (size_t)B_ * T_ * D_ * 2;
    __hip_bfloat16* sm = (__hip_bfloat16*)ws;  ws += (size_t)B_ * G_ * TPP_ * D_ * 2;
    __hip_bfloat16* smW = (__hip_bfloat16*)ws; ws += (size_t)B_ * G_ * TPP_ * D_ * 2;
    __hip_bfloat16* W1at = (__hip_bfloat16*)ws; ws += (size_t)D_ * D_ * 2;
    __hip_bfloat16* W1bt = (__hip_bfloat16*)ws; ws += (size_t)D_ * D_ * 2;
    int* glist = (int*)ws;                     ws += B_ * P_ * 4;
    int* goff  = (int*)ws;                     ws += B_ * (G_ + 1) * 4;

    prep_all<<<11091, 256, 0, stream>>>(
        answer, W_p, b_p, W_t, b_t, W1, qps, tids, mask, b2,
        Wpe_nat, Wbig, c_p, c_t, qb, W1at, W1bt, glist, goff, out);
    stage2<<<192, 256, 0, stream>>>(W1at, Wpe_nat, Wbig, c_p, W1, b1, cc);
    gemm_ts<<<dim3(T_ / 128, D_ / 128, B_), 256, 0, stream>>>(qb, Wbig, c_t, ts);
    segmax_kernel<<<(B_ * TPP_ * (D_ / 4)) / 256, 256, 0, stream>>>(
        ts, glist, goff, sm);
    gemm_smw<<<dim3((B_ * G_ * TPP_) / 128, D_ / 128), 256, 0, stream>>>(
        sm, W1bt, smW);
    gemm_fin<<<dim3(T_ / 128, D_ / 128, B_), 256, 0, stream>>>(
        qb, Wbig, cc, smW, tids, W2, mask, out);
}

// Round 12
// 197.450 us; speedup vs baseline: 1.7489x; 1.1130x over previous
//
#include <hip/hip_runtime.h>
#include <hip/hip_bf16.h>

#define B_ 4
#define L_ 2
#define P_ 100
#define TPP_ 64
#define D_ 768
#define G_ 10
#define T_ (P_ * TPP_)   // 6400
#define NC_ (2 * D_)     // 1536

typedef __attribute__((ext_vector_type(8))) short bf16x8;
typedef __attribute__((ext_vector_type(4))) float f32x4;

__device__ __forceinline__ unsigned short f2bf(float f) {
    __hip_bfloat16 h = __float2bfloat16(f);
    return *reinterpret_cast<unsigned short*>(&h);
}
__device__ __forceinline__ float bfu2f(unsigned short u) {
    return __uint_as_float(((unsigned int)u) << 16);
}

__device__ __forceinline__ void gload_lds16(const void* g, void* l) {
    __builtin_amdgcn_global_load_lds(
        (const __attribute__((address_space(1))) void*)g,
        (__attribute__((address_space(3))) void*)l, 16, 0, 0);
}

#define SBAR()   __builtin_amdgcn_s_barrier()
#define SCHEDB() __builtin_amdgcn_sched_barrier(0)
#define VMCNT8() asm volatile("s_waitcnt vmcnt(8)" ::: "memory")
#define VMCNT0() asm volatile("s_waitcnt vmcnt(0)" ::: "memory")

// ---------------------------------------------------------------------------
// BK=64 stage + both-sides 8x16B-slot swizzle (validated r6/r8/r9)
// ---------------------------------------------------------------------------
__device__ __forceinline__ void stage64(
    const __hip_bfloat16* __restrict__ Ag, const __hip_bfloat16* __restrict__ Bg,
    int k0, __hip_bfloat16 (*As)[64], __hip_bfloat16 (*Bs)[64],
    int w, int row_l, int soff)
{
#pragma unroll
    for (int j = 0; j < 4; ++j) {
        int r = w * 32 + j * 8 + row_l;   // r&7 == row_l
        gload_lds16(Ag + (size_t)r * D_ + k0 + soff, &As[w * 32 + j * 8][0]);
        gload_lds16(Bg + (size_t)r * D_ + k0 + soff, &Bs[w * 32 + j * 8][0]);
    }
}

__device__ __forceinline__ void mfma_step64(
    __hip_bfloat16 (*As)[64], __hip_bfloat16 (*Bs)[64],
    int rr, int h, int wm, int wn, f32x4 acc[4][4])
{
#pragma unroll
    for (int ks = 0; ks < 2; ++ks) {
        const int rsl = (((ks << 2) + h) ^ (rr & 7)) << 3;
        bf16x8 af[4], bfr[4];
#pragma unroll
        for (int mi = 0; mi < 4; ++mi)
            af[mi] = *reinterpret_cast<const bf16x8*>(
                &As[wm * 64 + mi * 16 + rr][rsl]);
#pragma unroll
        for (int ni = 0; ni < 4; ++ni)
            bfr[ni] = *reinterpret_cast<const bf16x8*>(
                &Bs[wn * 64 + ni * 16 + rr][rsl]);
#pragma unroll
        for (int mi = 0; mi < 4; ++mi)
#pragma unroll
            for (int ni = 0; ni < 4; ++ni)
                acc[mi][ni] = __builtin_amdgcn_mfma_f32_16x16x32_bf16(
                    af[mi], bfr[ni], acc[mi][ni], 0, 0, 0);
    }
}

// setprio-wrapped MFMA cluster (catalog T5; phase-split structure present)
#define MFMA_STEP_P(As, Bs)                                                   \
    __builtin_amdgcn_s_setprio(1);                                            \
    mfma_step64(As, Bs, rr, h, wm, wn, acc);                                  \
    __builtin_amdgcn_s_setprio(0);

// ---------------------------------------------------------------------------
// T4 counted-vmcnt pipeline (validated r9): VMCNT(8) keeps next tile's 8
// loads in flight across the raw barriers; re-stage only after the barrier
// following the buffer's last read.
// ---------------------------------------------------------------------------
#define MFMA_LOOP_PIPE(Ag, Bg)                                                \
    {                                                                         \
        const int rr = lane & 15, h = lane >> 4;                              \
        const int row_l = lane >> 3;                                          \
        const int soff = ((lane & 7) ^ row_l) << 3;                           \
        stage64((Ag), (Bg), 0, As0, Bs0, w, row_l, soff);                     \
        stage64((Ag), (Bg), 64, As1, Bs1, w, row_l, soff);                    \
        SCHEDB();                                                             \
        for (int t = 0; t < 10; t += 2) {                                     \
            VMCNT8(); SBAR(); SCHEDB();                                       \
            MFMA_STEP_P(As0, Bs0);                                            \
            SCHEDB(); SBAR(); SCHEDB();                                       \
            stage64((Ag), (Bg), (t + 2) * 64, As0, Bs0, w, row_l, soff);      \
            SCHEDB();                                                         \
            VMCNT8(); SBAR(); SCHEDB();                                       \
            MFMA_STEP_P(As1, Bs1);                                            \
            SCHEDB(); SBAR(); SCHEDB();                                       \
            stage64((Ag), (Bg), (t + 3) * 64, As1, Bs1, w, row_l, soff);      \
            SCHEDB();                                                         \
        }                                                                     \
        VMCNT8(); SBAR(); SCHEDB();                                           \
        MFMA_STEP_P(As0, Bs0);                        /* tile 10 */           \
        SCHEDB();                                                             \
        VMCNT0(); SBAR(); SCHEDB();                                           \
        MFMA_STEP_P(As1, Bs1);                        /* tile 11 */           \
        __syncthreads();                                                      \
    }

#define DECL_LDS_DB()                                                         \
    __shared__ __align__(16) __hip_bfloat16 As0[128][64];                     \
    __shared__ __align__(16) __hip_bfloat16 Bs0[128][64];                     \
    __shared__ __align__(16) __hip_bfloat16 As1[128][64];                     \
    __shared__ __align__(16) __hip_bfloat16 Bs1[128][64];

#define DECL_ACC()                                                            \
    f32x4 acc[4][4];                                                          \
    _Pragma("unroll") for (int i = 0; i < 4; ++i)                             \
        _Pragma("unroll") for (int j = 0; j < 4; ++j)                         \
            _Pragma("unroll") for (int e = 0; e < 4; ++e) acc[i][j][e] = 0.0f;

// ---------------------------------------------------------------------------
// P-ALL (validated r9): wct / const / w1t / groups / out_init / conv_q fused.
// ---------------------------------------------------------------------------
__global__ __launch_bounds__(256) void prep_all(
    const float* __restrict__ answer, const float* __restrict__ W_p,
    const float* __restrict__ b_p, const float* __restrict__ W_t,
    const float* __restrict__ b_t, const float* __restrict__ W1,
    const float* __restrict__ qps, const int* __restrict__ tids,
    const float* __restrict__ mask, const float* __restrict__ b2,
    __hip_bfloat16* __restrict__ Wpe_nat, __hip_bfloat16* __restrict__ Wbig,
    float* __restrict__ c_p, float* __restrict__ c_t,
    __hip_bfloat16* __restrict__ qb, __hip_bfloat16* __restrict__ W1at,
    __hip_bfloat16* __restrict__ W1bt, int* __restrict__ glist,
    int* __restrict__ goff, float* __restrict__ out)
{
    __shared__ float lds[64][65];
    __shared__ float a_s[64];
    __shared__ float red2[2][4][64];
    __shared__ int g_cnt[B_][G_];
    __shared__ int g_off[B_][G_ + 1];
    __shared__ int g_cur[B_][G_];

    const int bid = blockIdx.x;
    const int tid = threadIdx.x;

    if (bid < 1152) {
        const int n0 = (bid % 24) * 64;
        const int k0 = ((bid / 24) % 12) * 64;
        const int b  = bid / 288;
        if (tid < 64) a_s[tid] = answer[((size_t)b * L_ + (L_ - 1)) * D_ + k0 + tid];
        __syncthreads();
        if (n0 < D_) {
#pragma unroll
            for (int i = 0; i < 16; ++i) {
                int k = (tid >> 6) + i * 4;
                int n = tid & 63;
                float v = W_p[(size_t)(D_ + k0 + k) * D_ + n0 + n] +
                          a_s[k] * W_p[(size_t)(2 * D_ + k0 + k) * D_ + n0 + n];
                Wpe_nat[(size_t)b * D_ * D_ + (size_t)(k0 + k) * D_ + n0 + n] =
                    __float2bfloat16(v);
            }
        } else {
            const int nn0 = n0 - D_;
#pragma unroll
            for (int i = 0; i < 16; ++i) {
                int k = (tid >> 6) + i * 4;
                int n = tid & 63;
                lds[k][n] = W_t[(size_t)(D_ + k0 + k) * D_ + nn0 + n] +
                            a_s[k] * W_t[(size_t)(2 * D_ + k0 + k) * D_ + nn0 + n];
            }
            __syncthreads();
#pragma unroll
            for (int j = 0; j < 16; ++j) {
                int n = (tid >> 6) + j * 4;
                int kk = tid & 63;
                Wbig[((size_t)b * NC_ + n0 + n) * D_ + k0 + kk] =
                    __float2bfloat16(lds[kk][n]);
            }
        }
    } else if (bid < 1200) {
        const int local = bid - 1152;
        const int b = local / 12;
        const int d = (local % 12) * 64 + (tid & 63);
        const int ks = tid >> 6;
        const float* a = answer + ((size_t)b * L_ + (L_ - 1)) * D_;
        float sp = 0.f, st = 0.f;
#pragma unroll 4
        for (int k = ks; k < D_; k += 4) {
            float av = a[k];
            sp += av * W_p[(size_t)k * D_ + d];
            st += av * W_t[(size_t)k * D_ + d];
        }
        red2[0][ks][tid & 63] = sp;
        red2[1][ks][tid & 63] = st;
        __syncthreads();
        if (ks == 0) {
            float s1 = b_p[d], s2 = b_t[d];
#pragma unroll
            for (int i = 0; i < 4; ++i) {
                s1 += red2[0][i][tid & 63];
                s2 += red2[1][i][tid & 63];
            }
            c_p[b * D_ + d] = s1;
            c_t[b * D_ + d] = s2;
        }
    } else if (bid < 1488) {
        const int local = bid - 1200;
        const int n0 = (local % 12) * 64;
        const int k0 = (local / 12) * 64;
#pragma unroll
        for (int i = 0; i < 16; ++i) {
            int k = (tid >> 6) + i * 4;
            int n = tid & 63;
            lds[k][n] = W1[(size_t)(k0 + k) * D_ + n0 + n];
        }
        __syncthreads();
        __hip_bfloat16* dst = (k0 < D_) ? W1at : W1bt;
        const int kk0 = (k0 < D_) ? k0 : k0 - D_;
#pragma unroll
        for (int j = 0; j < 16; ++j) {
            int n = (tid >> 6) + j * 4;
            int kk = tid & 63;
            dst[(size_t)(n0 + n) * D_ + kk0 + kk] = __float2bfloat16(lds[kk][n]);
        }
    } else if (bid == 1488) {
        if (tid < B_ * G_) g_cnt[tid / G_][tid % G_] = 0;
        __syncthreads();
        for (int i = tid; i < B_ * P_; i += 256)
            atomicAdd(&g_cnt[i / P_][tids[i]], 1);
        __syncthreads();
        if (tid < B_) {
            int o = 0;
            for (int g = 0; g < G_; ++g) { g_off[tid][g] = o; o += g_cnt[tid][g]; }
            g_off[tid][G_] = o;
            for (int g = 0; g <= G_; ++g) goff[tid * (G_ + 1) + g] = g_off[tid][g];
        }
        __syncthreads();
        if (tid < B_ * G_) g_cur[tid / G_][tid % G_] = g_off[tid / G_][tid % G_];
        __syncthreads();
        for (int i = tid; i < B_ * P_; i += 256) {
            int b = i / P_, p = i % P_;
            int slot = atomicAdd(&g_cur[b][tids[i]], 1);
            glist[b * P_ + slot] = p;
        }
    } else if (bid < 1491) {
        int bp = (bid - 1489) * 256 + tid;
        if (bp < B_ * P_) {
            float s = 0.f;
#pragma unroll 8
            for (int t = 0; t < TPP_; ++t) s += mask[(size_t)bp * TPP_ + t];
            out[bp] = s * b2[0];
        }
    } else {
        size_t base = ((size_t)(bid - 1491) * 256 + tid) * 8;
        int b = (int)(base / ((size_t)T_ * D_));
        size_t off = base % ((size_t)T_ * D_);
        const float4* src = reinterpret_cast<const float4*>(
            qps + ((size_t)b * L_ + (L_ - 1)) * (size_t)T_ * D_ + off);
        float4 v0 = src[0], v1 = src[1];
        bf16x8 o;
        o[0] = (short)f2bf(v0.x); o[1] = (short)f2bf(v0.y);
        o[2] = (short)f2bf(v0.z); o[3] = (short)f2bf(v0.w);
        o[4] = (short)f2bf(v1.x); o[5] = (short)f2bf(v1.y);
        o[6] = (short)f2bf(v1.z); o[7] = (short)f2bf(v1.w);
        *reinterpret_cast<bf16x8*>(&qb[base]) = o;
    }
}

// ---------------------------------------------------------------------------
// FUSED K2: blocks [0,1200) = gemm_ts (XCD-swizzled, tn-fastest decode);
//           [1200,1344) = gemm_c1 (Wbig lower half); [1344,1392) = prep_cc.
// ---------------------------------------------------------------------------
__global__ __launch_bounds__(256) void fused_ts_c1(
    const __hip_bfloat16* __restrict__ qb, __hip_bfloat16* __restrict__ Wbig,
    const float* __restrict__ c_t, __hip_bfloat16* __restrict__ ts,
    const __hip_bfloat16* __restrict__ W1at,
    const __hip_bfloat16* __restrict__ Wpe_nat,
    const float* __restrict__ c_p, const float* __restrict__ W1,
    const float* __restrict__ b1, float* __restrict__ cc)
{
    DECL_LDS_DB();
    __shared__ float red[4][64];
    const int bid = blockIdx.x;
    const int tid = threadIdx.x;
    const int lane = tid & 63, w = tid >> 6;
    const int wm = w & 1, wn = w >> 1;

    if (bid < 1200) {
        const int swz = (bid & 7) * 150 + (bid >> 3);
        const int tn = swz % 6;
        const int tmb = swz / 6;
        const int tm = tmb % 50, b = tmb / 50;
        DECL_ACC();
        const __hip_bfloat16* Ag = qb + (size_t)b * T_ * D_ + (size_t)tm * 128 * D_;
        const __hip_bfloat16* Bg =
            Wbig + (size_t)b * NC_ * D_ + (size_t)(D_ + tn * 128) * D_;
        MFMA_LOOP_PIPE(Ag, Bg);
#pragma unroll
        for (int mi = 0; mi < 4; ++mi)
#pragma unroll
            for (int ni = 0; ni < 4; ++ni) {
                int col = tn * 128 + wn * 64 + ni * 16 + (lane & 15);
                int rb  = tm * 128 + wm * 64 + mi * 16 + (lane >> 4) * 4;
                float cv = c_t[b * D_ + col];
#pragma unroll
                for (int e = 0; e < 4; ++e)
                    ts[((size_t)b * T_ + rb + e) * D_ + col] =
                        __float2bfloat16(acc[mi][ni][e] + cv);
            }
    } else if (bid < 1344) {
        const int local = bid - 1200;
        const int tm = local % 6, tn = (local / 6) % 6, b = local / 36;
        DECL_ACC();
        const __hip_bfloat16* Ag = W1at + (size_t)tm * 128 * D_;
        const __hip_bfloat16* Bg =
            Wpe_nat + (size_t)b * D_ * D_ + (size_t)tn * 128 * D_;
        MFMA_LOOP_PIPE(Ag, Bg);
#pragma unroll
        for (int mi = 0; mi < 4; ++mi)
#pragma unroll
            for (int ni = 0; ni < 4; ++ni) {
                int col = tn * 128 + wn * 64 + ni * 16 + (lane & 15);
                int row = tm * 128 + wm * 64 + mi * 16 + (lane >> 4) * 4;
#pragma unroll
                for (int e = 0; e < 4; ++e)
                    Wbig[(size_t)b * NC_ * D_ + (size_t)(row + e) * D_ + col] =
                        __float2bfloat16(acc[mi][ni][e]);
            }
    } else {
        const int local = bid - 1344;
        const int b = local / 12;
        const int n = (local % 12) * 64 + (tid & 63);
        const int ks = tid >> 6;
        float s = 0.f;
#pragma unroll 4
        for (int d = ks; d < D_; d += 4)
            s += c_p[b * D_ + d] * W1[(size_t)d * D_ + n];
        red[ks][tid & 63] = s;
        __syncthreads();
        if (ks == 0) {
            float tot = b1[n];
#pragma unroll
            for (int i = 0; i < 4; ++i) tot += red[i][tid & 63];
            cc[b * D_ + n] = tot;
        }
    }
}

// ---------------------------------------------------------------------------
// K3: segment max via group lists; 4 d's per thread
// ---------------------------------------------------------------------------
__global__ __launch_bounds__(256) void segmax_kernel(
    const __hip_bfloat16* __restrict__ ts, const int* __restrict__ glist,
    const int* __restrict__ goff, __hip_bfloat16* __restrict__ sm)
{
    int idx = blockIdx.x * 256 + threadIdx.x;
    int d4 = idx % (D_ / 4);
    int bt = idx / (D_ / 4);
    int t = bt % TPP_;
    int b = bt / TPP_;

    const ushort4* base =
        reinterpret_cast<const ushort4*>(ts + ((size_t)b * T_ + t) * D_) + d4;

    for (int g = 0; g < G_; ++g) {
        float m0 = -1e30f, m1 = -1e30f, m2 = -1e30f, m3 = -1e30f;
        int i0 = goff[b * (G_ + 1) + g], i1 = goff[b * (G_ + 1) + g + 1];
        for (int i = i0; i < i1; ++i) {
            int p = glist[b * P_ + i];
            ushort4 u = base[(size_t)p * TPP_ * (D_ / 4)];
            m0 = fmaxf(m0, bfu2f(u.x));
            m1 = fmaxf(m1, bfu2f(u.y));
            m2 = fmaxf(m2, bfu2f(u.z));
            m3 = fmaxf(m3, bfu2f(u.w));
        }
        ushort4 o;
        o.x = f2bf(m0); o.y = f2bf(m1); o.z = f2bf(m2); o.w = f2bf(m3);
        reinterpret_cast<ushort4*>(
            sm + (((size_t)b * G_ + g) * TPP_ + t) * D_)[d4] = o;
    }
}

// ---------------------------------------------------------------------------
// K4: smW = sm @ W1bt^T  (120 blocks, XCD-swizzled: 120 = 8*15)
// ---------------------------------------------------------------------------
__global__ __launch_bounds__(256) void gemm_smw(
    const __hip_bfloat16* __restrict__ sm, const __hip_bfloat16* __restrict__ W1bt,
    __hip_bfloat16* __restrict__ smW)
{
    const int swz = (blockIdx.x & 7) * 15 + (blockIdx.x >> 3);
    const int tn = swz % 6, tm = swz / 6;
    DECL_LDS_DB();
    const int tid = threadIdx.x;
    const int lane = tid & 63, w = tid >> 6;
    const int wm = w & 1, wn = w >> 1;
    DECL_ACC();

    const __hip_bfloat16* Ag = sm + (size_t)tm * 128 * D_;
    const __hip_bfloat16* Bg = W1bt + (size_t)tn * 128 * D_;
    MFMA_LOOP_PIPE(Ag, Bg);

#pragma unroll
    for (int mi = 0; mi < 4; ++mi)
#pragma unroll
        for (int ni = 0; ni < 4; ++ni) {
            int col = tn * 128 + wn * 64 + ni * 16 + (lane & 15);
            int rb  = tm * 128 + wm * 64 + mi * 16 + (lane >> 4) * 4;
#pragma unroll
            for (int e = 0; e < 4; ++e)
                smW[(size_t)(rb + e) * D_ + col] = __float2bfloat16(acc[mi][ni][e]);
        }
}

// ---------------------------------------------------------------------------
// K5: fused  acc = qb @ Wbig[b][0..768]^T ; v = relu(acc + cc + smW[g])
//     rowdot = v . W2 ; out[b][p] += sum_t mask * rowdot
//     1D launch (1200 blocks) matching the 1D XCD-swizzled decode.  <-- r11 fix
// ---------------------------------------------------------------------------
__global__ __launch_bounds__(256) void gemm_fin(
    const __hip_bfloat16* __restrict__ qb, const __hip_bfloat16* __restrict__ Wbig,
    const float* __restrict__ cc, const __hip_bfloat16* __restrict__ smW,
    const int* __restrict__ tids, const float* __restrict__ W2,
    const float* __restrict__ mask, float* __restrict__ out)
{
    const int swz = (blockIdx.x & 7) * 150 + (blockIdx.x >> 3);
    const int tn = swz % 6;
    const int tmb = swz / 6;
    const int tm = tmb % 50, b = tmb / 50;
    DECL_LDS_DB();
    __shared__ float rowsum[2][128];

    const int tid = threadIdx.x;
    const int lane = tid & 63, w = tid >> 6;
    const int wm = w & 1, wn = w >> 1;
    DECL_ACC();

    const __hip_bfloat16* Ag = qb + (size_t)b * T_ * D_ + (size_t)tm * 128 * D_;
    const __hip_bfloat16* Bg = Wbig + (size_t)b * NC_ * D_ + (size_t)tn * 128 * D_;
    MFMA_LOOP_PIPE(Ag, Bg);

    const int p = tm * 2 + wm;
    const int g = tids[b * P_ + p];
    const __hip_bfloat16* smWg = smW + ((size_t)(b * G_ + g) * TPP_) * D_;
    const int h = lane >> 4;

    float rs[4][4];
#pragma unroll
    for (int mi = 0; mi < 4; ++mi)
#pragma unroll
        for (int e = 0; e < 4; ++e) rs[mi][e] = 0.f;

#pragma unroll
    for (int ni = 0; ni < 4; ++ni) {
        int col = tn * 128 + wn * 64 + ni * 16 + (lane & 15);
        float ccv = cc[b * D_ + col];
        float w2v = W2[col];
#pragma unroll
        for (int mi = 0; mi < 4; ++mi)
#pragma unroll
            for (int e = 0; e < 4; ++e) {
                int trow = mi * 16 + h * 4 + e;
                float v = acc[mi][ni][e] + ccv +
                          bfu2f(*reinterpret_cast<const unsigned short*>(
                              &smWg[(size_t)trow * D_ + col]));
                rs[mi][e] += fmaxf(v, 0.f) * w2v;
            }
    }
#pragma unroll
    for (int off = 8; off >= 1; off >>= 1)
#pragma unroll
        for (int mi = 0; mi < 4; ++mi)
#pragma unroll
            for (int e = 0; e < 4; ++e) rs[mi][e] += __shfl_xor(rs[mi][e], off);

    if ((lane & 15) == 0) {
#pragma unroll
        for (int mi = 0; mi < 4; ++mi)
#pragma unroll
            for (int e = 0; e < 4; ++e)
                rowsum[wn][wm * 64 + mi * 16 + h * 4 + e] = rs[mi][e];
    }
    __syncthreads();

    if (tid < 128) {
        int pp = tid >> 6, t = tid & 63;
        float v = (rowsum[0][tid] + rowsum[1][tid]) *
                  mask[((size_t)b * P_ + tm * 2 + pp) * TPP_ + t];
#pragma unroll
        for (int off = 32; off >= 1; off >>= 1) v += __shfl_xor(v, off);
        if (t == 0) atomicAdd(&out[b * P_ + tm * 2 + pp], v);
    }
}

// ---------------------------------------------------------------------------
extern "C" void kernel_launch(void* const* d_in, const int* in_sizes, int n_in,
                              void* d_out, int out_size, void* d_ws, size_t ws_size,
                              hipStream_t stream)
{
    const float* answer = (const float*)d_in[0];
    const float* qps    = (const float*)d_in[1];
    const float* mask   = (const float*)d_in[2];
    const int*   tids   = (const int*)d_in[3];
    // d_in[4] = fusion_scores: unused by the reference
    const float* W_p = (const float*)d_in[5];
    const float* b_p = (const float*)d_in[6];
    const float* W_t = (const float*)d_in[7];
    const float* b_t = (const float*)d_in[8];
    const float* W1  = (const float*)d_in[9];
    const float* b1  = (const float*)d_in[10];
    const float* W2  = (const float*)d_in[11];
    const float* b2  = (const float*)d_in[12];
    float* out = (float*)d_out;

    char* ws = (char*)d_ws;
    __hip_bfloat16* Wpe_nat = (__hip_bfloat16*)ws; ws += (size_t)B_ * D_ * D_ * 2;
    __hip_bfloat16* Wbig    = (__hip_bfloat16*)ws; ws += (size_t)B_ * NC_ * D_ * 2;
    float* c_p = (float*)ws;                   ws += (size_t)B_ * D_ * 4;
    float* c_t = (float*)ws;                   ws += (size_t)B_ * D_ * 4;
    float* cc  = (float*)ws;                   ws += (size_t)B_ * D_ * 4;
    __hip_bfloat16* qb = (__hip_bfloat16*)ws;  ws += (size_t)B_ * T_ * D_ * 2;
    __hip_bfloat16* ts = (__hip_bfloat16*)ws;  ws += (size_t)B_ * T_ * D_ * 2;
    __hip_bfloat16* sm = (__hip_bfloat16*)ws;  ws += (size_t)B_ * G_ * TPP_ * D_ * 2;
    __hip_bfloat16* smW = (__hip_bfloat16*)ws; ws += (size_t)B_ * G_ * TPP_ * D_ * 2;
    __hip_bfloat16* W1at = (__hip_bfloat16*)ws; ws += (size_t)D_ * D_ * 2;
    __hip_bfloat16* W1bt = (__hip_bfloat16*)ws; ws += (size_t)D_ * D_ * 2;
    int* glist = (int*)ws;                     ws += B_ * P_ * 4;
    int* goff  = (int*)ws;                     ws += B_ * (G_ + 1) * 4;

    prep_all<<<11091, 256, 0, stream>>>(
        answer, W_p, b_p, W_t, b_t, W1, qps, tids, mask, b2,
        Wpe_nat, Wbig, c_p, c_t, qb, W1at, W1bt, glist, goff, out);
    fused_ts_c1<<<1392, 256, 0, stream>>>(
        qb, Wbig, c_t, ts, W1at, Wpe_nat, c_p, W1, b1, cc);
    segmax_kernel<<<(B_ * TPP_ * (D_ / 4)) / 256, 256, 0, stream>>>(
        ts, glist, goff, sm);
    gemm_smw<<<120, 256, 0, stream>>>(sm, W1bt, smW);
    gemm_fin<<<1200, 256, 0, stream>>>(
        qb, Wbig, cc, smW, tids, W2, mask, out);
}